// Round 5
// baseline (415.459 us; speedup 1.0000x reference)
//
#include <hip/hip_runtime.h>
#include <math.h>

#define N 1536
#define E 24576
#define HD 128
#define D 1280
#define NW 24    // 1536/64 bitmask words per row
#define RT 16    // rows per block in k_h
#define NCH 8    // j-chunks in k_h2 (192 cols/chunk -> 0.96MB, one chunk per XCD)
#define CHW 192  // chunk width

typedef unsigned long long u64;
typedef unsigned short u16;

__device__ __forceinline__ double lrelu(double v){ return v > 0.0 ? v : 0.2*v; }

__device__ __forceinline__ int lbound(const u16* __restrict__ a, int n, int v){
    int lo = 0;
    while (lo < n){ int mid = (lo + n) >> 1; if (a[mid] < v) lo = mid + 1; else n = mid; }
    return lo;
}

// ---- IN bitmask (in-neighbors from the E raw edges) + in-degree incl. self-loop
__global__ void k_deg_in(const int* __restrict__ ei, u64* __restrict__ IN, int* __restrict__ deg){
    int idx = blockIdx.x*blockDim.x + threadIdx.x;
    if (idx < E){
        int s = ei[idx], t = ei[E+idx];
        atomicOr(&IN[(size_t)t*NW + (s>>6)], 1ULL << (s&63));
        atomicAdd(&deg[t], 1);
    } else if (idx < E+N){
        atomicAdd(&deg[idx-E], 1);
    }
}

// ---- exclusive scan of deg (1536 entries) -> coff[0..N], cursor copy
__global__ void k_scan(const int* __restrict__ deg, int* __restrict__ coff, int* __restrict__ cursor){
    __shared__ int ls[256];
    int tid = threadIdx.x;
    int v[6]; int s = 0;
    for (int u=0; u<6; u++){ v[u] = s; s += deg[tid*6+u]; }
    ls[tid] = s; __syncthreads();
    for (int d=1; d<256; d<<=1){
        int t2 = (tid>=d) ? ls[tid-d] : 0;
        __syncthreads();
        ls[tid] += t2;
        __syncthreads();
    }
    int base = (tid>0) ? ls[tid-1] : 0;
    for (int u=0; u<6; u++){
        int o = base + v[u];
        coff[tid*6+u] = o; cursor[tid*6+u] = o;
    }
    if (tid==255) coff[N] = ls[255];
}

// ---- fill CSR of in-edge sources (duplicates preserved; self-loops appended)
__global__ void k_fill(const int* __restrict__ ei, int* __restrict__ cursor, int* __restrict__ csr_src){
    int idx = blockIdx.x*blockDim.x + threadIdx.x;
    if (idx < E){
        int s = ei[idx], t = ei[E+idx];
        int p = atomicAdd(&cursor[t], 1);
        csr_src[p] = s;
    } else if (idx < E+N){
        int t = idx - E;
        int p = atomicAdd(&cursor[t], 1);
        csr_src[p] = t;
    }
}

// ---- 2-hop reachability. v2: 1-hop node list in LDS, 4 independent OR chains.
__global__ void k_mrow(const u64* __restrict__ IN, u64* __restrict__ Mb,
                       u16* __restrict__ cols, int* __restrict__ cnt){
    int i = blockIdx.x, ln = threadIdx.x;   // blockDim = 64
    __shared__ u64 m1[NW];
    __shared__ int scn[64];
    __shared__ u16 lst[N];
    u64 b = 0;
    if (ln < NW){
        b = IN[(size_t)i*NW + ln];
        if ((i>>6) == ln) b |= 1ULL << (i&63);
        m1[ln] = b;
    }
    int pc = (ln < NW) ? __popcll(b) : 0;
    scn[ln] = pc; __syncthreads();
    for (int d=1; d<64; d<<=1){
        int v = (ln>=d) ? scn[ln-d] : 0;
        __syncthreads();
        scn[ln] += v;
        __syncthreads();
    }
    // lane-parallel extraction of 1-hop node list
    {
        int idx = scn[ln] - pc;
        u64 bb = b;
        while (bb){
            int k = __ffsll((unsigned long long)bb) - 1;
            bb &= bb - 1;
            lst[idx++] = (u16)(ln*64 + k);
        }
    }
    __syncthreads();
    int nn = scn[63];
    // union of IN rows over the list: 4 independent accumulation chains
    u64 R0 = b, R1 = 0, R2 = 0, R3 = 0;
    int u = 0;
    if (ln < NW){
        for (; u+3 < nn; u += 4){
            R0 |= IN[(size_t)lst[u  ]*NW + ln];
            R1 |= IN[(size_t)lst[u+1]*NW + ln];
            R2 |= IN[(size_t)lst[u+2]*NW + ln];
            R3 |= IN[(size_t)lst[u+3]*NW + ln];
        }
        for (; u < nn; u++) R0 |= IN[(size_t)lst[u]*NW + ln];
    }
    u64 R = (R0 | R1) | (R2 | R3);
    if (ln < NW) Mb[(size_t)i*NW + ln] = R;
    __syncthreads();
    pc = (ln < NW) ? __popcll(R) : 0;
    scn[ln] = pc; __syncthreads();
    for (int d=1; d<64; d<<=1){
        int v = (ln>=d) ? scn[ln-d] : 0;
        __syncthreads();
        scn[ln] += v;
        __syncthreads();
    }
    if (ln == 63) cnt[i] = scn[63];
    int idx = scn[ln] - pc;
    u64 bb = R;
    while (bb){
        int k = __ffsll((unsigned long long)bb) - 1;
        bb &= bb - 1;
        cols[(size_t)i*N + idx++] = (u16)(ln*64 + k);
    }
}

// ---- h = x @ W1 (f64). grid (D/256, N/RT). 16 rows/block: W1 reuse + 16 indep chains.
__global__ void k_h(const float* __restrict__ x, const float* __restrict__ W1, double* __restrict__ h64){
    int rb = blockIdx.y*RT, tid = threadIdx.x;
    int col = blockIdx.x*256 + tid;
    __shared__ double xL[RT*HD];   // 16 KB
    for (int u=tid; u<RT*HD; u+=256) xL[u] = (double)x[(size_t)rb*HD + u];
    __syncthreads();
    double acc[RT];
    #pragma unroll
    for (int r=0; r<RT; r++) acc[r] = 0.0;
    const float* wp = &W1[col];
    #pragma unroll 4
    for (int k=0; k<HD; k++){
        double w = (double)wp[(size_t)k*D];
        #pragma unroll
        for (int r=0; r<RT; r++) acc[r] += w * xL[r*HD + k];  // LDS broadcast
    }
    #pragma unroll
    for (int r=0; r<RT; r++) h64[(size_t)(rb+r)*D + col] = acc[r];
}

// ---- hs1 = h@a_src1, hd1 = h@a_dst1
__global__ void k_hv(const double* __restrict__ h64, const float* __restrict__ as1,
                     const float* __restrict__ ad1, double* __restrict__ hs1, double* __restrict__ hd1){
    int i = blockIdx.x, tid = threadIdx.x;
    __shared__ double ra[256], rb[256];
    double a = 0, b = 0;
    for (int d=tid; d<D; d+=256){
        double hv = h64[(size_t)i*D + d];
        a += hv * (double)as1[d];
        b += hv * (double)ad1[d];
    }
    ra[tid] = a; rb[tid] = b; __syncthreads();
    for (int s=128; s>0; s>>=1){
        if (tid < s){ ra[tid] += ra[tid+s]; rb[tid] += rb[tid+s]; }
        __syncthreads();
    }
    if (tid == 0){ hs1[i] = ra[0]; hd1[i] = rb[0]; }
}

// ---- stage-1 GAT gather per target; 2-way unrolled accumulation (10 loads in flight)
__global__ void k_gat(const int* __restrict__ coff, const int* __restrict__ csr_src,
                      const double* __restrict__ hs1, const double* __restrict__ hd1,
                      const double* __restrict__ h64,
                      const float* __restrict__ b1, const float* __restrict__ w2,
                      double* __restrict__ g64){
    int t = blockIdx.x, tid = threadIdx.x;
    int o0 = coff[t], o1 = coff[t+1], dg = o1 - o0;
    __shared__ double ms[256], ds[256], als[256];
    __shared__ int ssrc[256];
    __shared__ double MM, DD;
    double hdt = hd1[t];
    double m = -INFINITY, dsum = 0.0;
    for (int j=tid; j<dg; j+=256){
        int s = csr_src[o0+j];
        double e = lrelu(hs1[s] + hdt);
        if (e > m){ dsum = dsum*exp(m-e) + 1.0; m = e; }
        else dsum += exp(e-m);
    }
    ms[tid] = m; ds[tid] = dsum; __syncthreads();
    for (int step=128; step>0; step>>=1){
        if (tid < step){
            double m1 = ms[tid], d1 = ds[tid];
            double m2 = ms[tid+step], d2 = ds[tid+step];
            double M = fmax(m1, m2), Dv = 0.0;
            if (d1 > 0.0) Dv += d1*exp(m1-M);
            if (d2 > 0.0) Dv += d2*exp(m2-M);
            ms[tid] = M; ds[tid] = Dv;
        }
        __syncthreads();
    }
    if (tid == 0){ MM = ms[0]; DD = ds[0]; }
    __syncthreads();
    double M = MM, Dv = DD;
    double acc[5] = {0,0,0,0,0};
    for (int base=0; base<dg; base+=256){
        int j = base + tid;
        if (j < dg){
            int s = csr_src[o0+j];
            double e = lrelu(hs1[s] + hdt);
            als[tid] = exp(e-M)/Dv; ssrc[tid] = s;
        }
        __syncthreads();
        int lim = min(256, dg-base);
        for (int u=0; u<lim; u+=2){
            double a0 = als[u];
            int s0 = ssrc[u];
            bool h1 = (u+1 < lim);
            double a1 = h1 ? als[u+1] : 0.0;
            int s1 = h1 ? ssrc[u+1] : s0;
            const double* hp0 = &h64[(size_t)s0*D];
            const double* hp1 = &h64[(size_t)s1*D];
            #pragma unroll
            for (int q=0; q<5; q++)
                acc[q] += a0 * hp0[tid + 256*q] + a1 * hp1[tid + 256*q];
        }
        __syncthreads();
    }
    #pragma unroll
    for (int q=0; q<5; q++){
        int d = tid + 256*q;
        g64[(size_t)t*D + d] = (acc[q] + (double)b1[d]) * (double)w2[d];
    }
}

// ---- sparse H2: v4 — 8 chunks (0.96MB/XCD), 4 cols/iteration = 20 loads in flight.
__global__ __launch_bounds__(256, 2)
void k_h2(const double* __restrict__ g64, const float* __restrict__ xo,
          const u16* __restrict__ cols, const int* __restrict__ cnt,
          double* __restrict__ H2){
    int b = blockIdx.x;
    int chunk = b & (NCH-1);
    int tid = threadIdx.x, wv = tid >> 6, ln = tid & 63;
    int i = ((b >> 3) << 2) + wv;
    double gr[5][4];
    #pragma unroll
    for (int k=0; k<5; k++){
        #pragma unroll
        for (int c=0; c<4; c++) gr[k][c] = g64[(size_t)i*D + ln*4 + 256*k + c];
    }
    int c0 = cnt[i];
    const u16* cp = &cols[(size_t)i*N];
    int v0 = chunk*CHW;
    int lo = lbound(cp, c0, v0);
    int hi = lbound(cp, c0, v0 + CHW);
    for (int cb = lo; cb < hi; cb += 4){
        int e1 = (cb+1 < hi) ? cb+1 : cb;
        int e2 = (cb+2 < hi) ? cb+2 : cb;
        int e3 = (cb+3 < hi) ? cb+3 : cb;
        int j0 = cp[cb], j1 = cp[e1], j2 = cp[e2], j3 = cp[e3];
        const float4* p0 = (const float4*)(&xo[(size_t)j0*D]) + ln;
        const float4* p1 = (const float4*)(&xo[(size_t)j1*D]) + ln;
        const float4* p2 = (const float4*)(&xo[(size_t)j2*D]) + ln;
        const float4* p3 = (const float4*)(&xo[(size_t)j3*D]) + ln;
        double a0 = 0.0, a1 = 0.0, a2 = 0.0, a3 = 0.0;
        #pragma unroll
        for (int k=0; k<5; k++){
            float4 w0 = p0[64*k];
            float4 w1 = p1[64*k];
            float4 w2v = p2[64*k];
            float4 w3 = p3[64*k];
            a0 += gr[k][0]*(double)w0.x + gr[k][1]*(double)w0.y
                + gr[k][2]*(double)w0.z + gr[k][3]*(double)w0.w;
            a1 += gr[k][0]*(double)w1.x + gr[k][1]*(double)w1.y
                + gr[k][2]*(double)w1.z + gr[k][3]*(double)w1.w;
            a2 += gr[k][0]*(double)w2v.x + gr[k][1]*(double)w2v.y
                + gr[k][2]*(double)w2v.z + gr[k][3]*(double)w2v.w;
            a3 += gr[k][0]*(double)w3.x + gr[k][1]*(double)w3.y
                + gr[k][2]*(double)w3.z + gr[k][3]*(double)w3.w;
        }
        #pragma unroll
        for (int o=32; o>0; o>>=1){
            a0 += __shfl_down(a0, o, 64);
            a1 += __shfl_down(a1, o, 64);
            a2 += __shfl_down(a2, o, 64);
            a3 += __shfl_down(a3, o, 64);
        }
        if (ln == 0){
            H2[(size_t)i*N + j0] = a0;
            if (cb+1 < hi) H2[(size_t)i*N + j1] = a1;
            if (cb+2 < hi) H2[(size_t)i*N + j2] = a2;
            if (cb+3 < hi) H2[(size_t)i*N + j3] = a3;
        }
    }
}

// ---- fused stage-2 score + top-k rank + output (scores never leave LDS)
__global__ void k_score_rank(const double* __restrict__ H2, const u64* __restrict__ Mb,
                             const u16* __restrict__ cols, const int* __restrict__ cnt,
                             const int* __restrict__ coff, const int* __restrict__ csr_src,
                             const float* __restrict__ pas2, const float* __restrict__ pad2,
                             const float* __restrict__ pb2, float* __restrict__ out){
    int i = blockIdx.x, tid = threadIdx.x;
    __shared__ double HL[N];     // 12 KB
    __shared__ u64 MbL[NW];
    __shared__ double scL[N];    // 12 KB
    __shared__ u16 clL[N];       // 3 KB
    float* keepO = out + (size_t)N*N;
    // zero this block's output rows (replaces global d_out memset)
    for (int c=tid; c<N; c+=256){
        out[(size_t)i*N + c]   = 0.0f;
        keepO[(size_t)i*N + c] = 0.0f;
    }
    for (int d=tid; d<N; d+=256) HL[d] = H2[(size_t)i*N + d];
    if (tid < NW) MbL[tid] = Mb[(size_t)i*NW + tid];
    __syncthreads();
    double as2 = (double)pas2[0], ad2 = (double)pad2[0], b2 = (double)pb2[0];
    int c0 = cnt[i];
    for (int c=tid; c<c0; c+=256){
        int t = cols[(size_t)i*N + c];
        double ht = HL[t];
        int o0 = coff[t], o1 = coff[t+1];
        double m = -INFINITY, den = 0.0, nu = 0.0;
        for (int p=o0; p<o1; p++){
            int s = csr_src[p];
            if ((MbL[s>>6] >> (s&63)) & 1ULL){
                double hs = HL[s];
                double z = as2*hs + ad2*ht;
                double e = z > 0.0 ? z : 0.2*z;
                if (e > m){
                    double sc = exp(m-e);     // exp(-inf)=0 on first valid edge
                    den = den*sc + 1.0;
                    nu  = nu*sc + hs;
                    m = e;
                } else {
                    double w = exp(e-m);
                    den += w; nu += w*hs;
                }
            }
        }
        scL[c] = nu / fmax(den, 1e-12) + b2;
        clL[c] = (u16)t;
    }
    __syncthreads();
    int k = (c0 + 1) >> 1;                 // ceil(0.5*size)
    for (int p=tid; p<c0; p+=256){
        double s = scL[p]; int col = clL[p];
        int r = 0;
        for (int q=0; q<c0; q++){
            double sq = scL[q];
            r += (sq > s) || (sq == s && clL[q] < col);
        }
        if (r < k){
            out[(size_t)i*N + col]   = (float)(1.0/(1.0 + exp(-s)));
            keepO[(size_t)i*N + col] = 1.0f;
        }
    }
}

extern "C" void kernel_launch(void* const* d_in, const int* in_sizes, int n_in,
                              void* d_out, int out_size, void* d_ws, size_t ws_size,
                              hipStream_t stream){
    const float* x   = (const float*)d_in[0];
    const float* xo  = (const float*)d_in[1];
    const int*   ei  = (const int*)  d_in[2];
    // d_in[3] = batch (unused)
    const float* W1  = (const float*)d_in[4];
    const float* as1 = (const float*)d_in[5];
    const float* ad1 = (const float*)d_in[6];
    const float* b1  = (const float*)d_in[7];
    const float* w2  = (const float*)d_in[8];
    const float* as2 = (const float*)d_in[9];
    const float* ad2 = (const float*)d_in[10];
    const float* b2  = (const float*)d_in[11];
    float* out = (float*)d_out;

    char* w = (char*)d_ws;
    size_t o = 0;
    auto alloc = [&](size_t b)->char*{ char* r = w + o; o = (o + b + 255) & ~(size_t)255; return r; };

    double* h64   = (double*)alloc((size_t)N*D*8);   // dead after k_gat
    double* g64   = (double*)alloc((size_t)N*D*8);   // dead after k_h2
    double* H2    = (double*)alloc((size_t)N*N*8);
    u64*    IN    = (u64*)   alloc((size_t)N*NW*8);
    u64*    Mb    = (u64*)   alloc((size_t)N*NW*8);
    double* hs1   = (double*)alloc((size_t)N*8);
    double* hd1   = (double*)alloc((size_t)N*8);
    int*    deg   = (int*)   alloc((size_t)N*4);
    int*    coff  = (int*)   alloc((size_t)(N+1)*4);
    int*    cursor= (int*)   alloc((size_t)N*4);
    int*    csr   = (int*)   alloc((size_t)(E+N)*4);
    u16*    cols  = (u16*)   alloc((size_t)N*N*2);
    int*    cnt   = (int*)   alloc((size_t)N*4);

    hipMemsetAsync(IN,  0, (size_t)N*NW*8, stream);
    hipMemsetAsync(deg, 0, (size_t)N*4,    stream);

    k_deg_in<<<(E+N+255)/256, 256, 0, stream>>>(ei, IN, deg);
    k_scan  <<<1, 256, 0, stream>>>(deg, coff, cursor);
    k_fill  <<<(E+N+255)/256, 256, 0, stream>>>(ei, cursor, csr);
    k_mrow  <<<N, 64, 0, stream>>>(IN, Mb, cols, cnt);
    k_h     <<<dim3(D/256, N/RT), 256, 0, stream>>>(x, W1, h64);
    k_hv    <<<N, 256, 0, stream>>>(h64, as1, ad1, hs1, hd1);
    k_gat   <<<N, 256, 0, stream>>>(coff, csr, hs1, hd1, h64, b1, w2, g64);
    k_h2    <<<(N/4)*NCH, 256, 0, stream>>>(g64, xo, cols, cnt, H2);
    k_score_rank<<<N, 256, 0, stream>>>(H2, Mb, cols, cnt, coff, csr, as2, ad2, b2, out);
}

// Round 6
// 381.794 us; speedup vs baseline: 1.0882x; 1.0882x over previous
//
#include <hip/hip_runtime.h>
#include <math.h>

#define N 1536
#define E 24576
#define HD 128
#define D 1280
#define NW 24    // 1536/64 bitmask words per row
#define RT 16    // rows per block in k_h
#define NCH 8    // j-chunks in k_h2
#define CHW 192  // chunk width

typedef unsigned long long u64;
typedef unsigned short u16;

__device__ __forceinline__ double lrelu(double v){ return v > 0.0 ? v : 0.2*v; }

// Branch-free exp(x), rel err ~6e-15. Valid for x in [-700, +700]; x < -700 -> 0.
// No libm call, no divergence: ~14 f64 FMA + exponent build.
__device__ __forceinline__ double fexp(double x){
    double n = __builtin_rint(x * 1.4426950408889634);
    double r = __builtin_fma(-n, 0.6931471805599453, x);
    r = __builtin_fma(-n, 2.3190468138462996e-17, r);
    double p = 2.505210838544172e-8;                    // 1/11!
    p = __builtin_fma(p, r, 2.755731922398589e-7);      // 1/10!
    p = __builtin_fma(p, r, 2.7557319223985893e-6);     // 1/9!
    p = __builtin_fma(p, r, 2.48015873015873e-5);       // 1/8!
    p = __builtin_fma(p, r, 1.984126984126984e-4);      // 1/7!
    p = __builtin_fma(p, r, 1.3888888888888889e-3);     // 1/6!
    p = __builtin_fma(p, r, 8.333333333333333e-3);      // 1/5!
    p = __builtin_fma(p, r, 4.1666666666666664e-2);     // 1/4!
    p = __builtin_fma(p, r, 1.6666666666666666e-1);     // 1/3!
    p = __builtin_fma(p, r, 0.5);
    p = __builtin_fma(p, r, 1.0);
    p = __builtin_fma(p, r, 1.0);                        // wrong? see below
    // NOTE: last two lines implement ((..)*r + 1)*r + 1 = poly with c1=1, c0=1 — correct Taylor.
    long long ni = (long long)n;
    double s = __longlong_as_double((u64)(ni + 1023) << 52);
    return (x < -700.0) ? 0.0 : p * s;
}

__device__ __forceinline__ int lbound(const u16* __restrict__ a, int n, int v){
    int lo = 0;
    while (lo < n){ int mid = (lo + n) >> 1; if (a[mid] < v) lo = mid + 1; else n = mid; }
    return lo;
}

// ---- IN bitmask (in-neighbors from the E raw edges) + in-degree incl. self-loop
__global__ void k_deg_in(const int* __restrict__ ei, u64* __restrict__ IN, int* __restrict__ deg){
    int idx = blockIdx.x*blockDim.x + threadIdx.x;
    if (idx < E){
        int s = ei[idx], t = ei[E+idx];
        atomicOr(&IN[(size_t)t*NW + (s>>6)], 1ULL << (s&63));
        atomicAdd(&deg[t], 1);
    } else if (idx < E+N){
        atomicAdd(&deg[idx-E], 1);
    }
}

// ---- exclusive scan of deg (1536 entries) -> coff[0..N], cursor copy
__global__ void k_scan(const int* __restrict__ deg, int* __restrict__ coff, int* __restrict__ cursor){
    __shared__ int ls[256];
    int tid = threadIdx.x;
    int v[6]; int s = 0;
    for (int u=0; u<6; u++){ v[u] = s; s += deg[tid*6+u]; }
    ls[tid] = s; __syncthreads();
    for (int d=1; d<256; d<<=1){
        int t2 = (tid>=d) ? ls[tid-d] : 0;
        __syncthreads();
        ls[tid] += t2;
        __syncthreads();
    }
    int base = (tid>0) ? ls[tid-1] : 0;
    for (int u=0; u<6; u++){
        int o = base + v[u];
        coff[tid*6+u] = o; cursor[tid*6+u] = o;
    }
    if (tid==255) coff[N] = ls[255];
}

// ---- fill CSR of in-edge sources (duplicates preserved; self-loops appended)
__global__ void k_fill(const int* __restrict__ ei, int* __restrict__ cursor, int* __restrict__ csr_src){
    int idx = blockIdx.x*blockDim.x + threadIdx.x;
    if (idx < E){
        int s = ei[idx], t = ei[E+idx];
        int p = atomicAdd(&cursor[t], 1);
        csr_src[p] = s;
    } else if (idx < E+N){
        int t = idx - E;
        int p = atomicAdd(&cursor[t], 1);
        csr_src[p] = t;
    }
}

// ---- 2-hop reachability. 1-hop node list in LDS, 4 independent OR chains.
__global__ void k_mrow(const u64* __restrict__ IN, u64* __restrict__ Mb,
                       u16* __restrict__ cols, int* __restrict__ cnt){
    int i = blockIdx.x, ln = threadIdx.x;   // blockDim = 64
    __shared__ u64 m1[NW];
    __shared__ int scn[64];
    __shared__ u16 lst[N];
    u64 b = 0;
    if (ln < NW){
        b = IN[(size_t)i*NW + ln];
        if ((i>>6) == ln) b |= 1ULL << (i&63);
        m1[ln] = b;
    }
    int pc = (ln < NW) ? __popcll(b) : 0;
    scn[ln] = pc; __syncthreads();
    for (int d=1; d<64; d<<=1){
        int v = (ln>=d) ? scn[ln-d] : 0;
        __syncthreads();
        scn[ln] += v;
        __syncthreads();
    }
    {
        int idx = scn[ln] - pc;
        u64 bb = b;
        while (bb){
            int k = __ffsll((unsigned long long)bb) - 1;
            bb &= bb - 1;
            lst[idx++] = (u16)(ln*64 + k);
        }
    }
    __syncthreads();
    int nn = scn[63];
    u64 R0 = b, R1 = 0, R2 = 0, R3 = 0;
    int u = 0;
    if (ln < NW){
        for (; u+3 < nn; u += 4){
            R0 |= IN[(size_t)lst[u  ]*NW + ln];
            R1 |= IN[(size_t)lst[u+1]*NW + ln];
            R2 |= IN[(size_t)lst[u+2]*NW + ln];
            R3 |= IN[(size_t)lst[u+3]*NW + ln];
        }
        for (; u < nn; u++) R0 |= IN[(size_t)lst[u]*NW + ln];
    }
    u64 R = (R0 | R1) | (R2 | R3);
    if (ln < NW) Mb[(size_t)i*NW + ln] = R;
    __syncthreads();
    pc = (ln < NW) ? __popcll(R) : 0;
    scn[ln] = pc; __syncthreads();
    for (int d=1; d<64; d<<=1){
        int v = (ln>=d) ? scn[ln-d] : 0;
        __syncthreads();
        scn[ln] += v;
        __syncthreads();
    }
    if (ln == 63) cnt[i] = scn[63];
    int idx = scn[ln] - pc;
    u64 bb = R;
    while (bb){
        int k = __ffsll((unsigned long long)bb) - 1;
        bb &= bb - 1;
        cols[(size_t)i*N + idx++] = (u16)(ln*64 + k);
    }
}

// ---- h = x @ W1 (f64). grid (D/256, N/RT).
__global__ void k_h(const float* __restrict__ x, const float* __restrict__ W1, double* __restrict__ h64){
    int rb = blockIdx.y*RT, tid = threadIdx.x;
    int col = blockIdx.x*256 + tid;
    __shared__ double xL[RT*HD];   // 16 KB
    for (int u=tid; u<RT*HD; u+=256) xL[u] = (double)x[(size_t)rb*HD + u];
    __syncthreads();
    double acc[RT];
    #pragma unroll
    for (int r=0; r<RT; r++) acc[r] = 0.0;
    const float* wp = &W1[col];
    #pragma unroll 4
    for (int k=0; k<HD; k++){
        double w = (double)wp[(size_t)k*D];
        #pragma unroll
        for (int r=0; r<RT; r++) acc[r] += w * xL[r*HD + k];
    }
    #pragma unroll
    for (int r=0; r<RT; r++) h64[(size_t)(rb+r)*D + col] = acc[r];
}

// ---- hs1 = h@a_src1, hd1 = h@a_dst1
__global__ void k_hv(const double* __restrict__ h64, const float* __restrict__ as1,
                     const float* __restrict__ ad1, double* __restrict__ hs1, double* __restrict__ hd1){
    int i = blockIdx.x, tid = threadIdx.x;
    __shared__ double ra[256], rb[256];
    double a = 0, b = 0;
    for (int d=tid; d<D; d+=256){
        double hv = h64[(size_t)i*D + d];
        a += hv * (double)as1[d];
        b += hv * (double)ad1[d];
    }
    ra[tid] = a; rb[tid] = b; __syncthreads();
    for (int s=128; s>0; s>>=1){
        if (tid < s){ ra[tid] += ra[tid+s]; rb[tid] += rb[tid+s]; }
        __syncthreads();
    }
    if (tid == 0){ hs1[i] = ra[0]; hd1[i] = rb[0]; }
}

// ---- stage-1 GAT: 2-phase (max, then fexp sums), branch-free exp
__global__ void k_gat(const int* __restrict__ coff, const int* __restrict__ csr_src,
                      const double* __restrict__ hs1, const double* __restrict__ hd1,
                      const double* __restrict__ h64,
                      const float* __restrict__ b1, const float* __restrict__ w2,
                      double* __restrict__ g64){
    int t = blockIdx.x, tid = threadIdx.x;
    int o0 = coff[t], o1 = coff[t+1], dg = o1 - o0;
    __shared__ double red[256], als[256];
    __shared__ int ssrc[256];
    __shared__ double MM, DD;
    double hdt = hd1[t];
    // phase 1: max
    double m = -1e300;
    for (int j=tid; j<dg; j+=256){
        int s = csr_src[o0+j];
        double e = lrelu(hs1[s] + hdt);
        m = fmax(m, e);
    }
    red[tid] = m; __syncthreads();
    for (int step=128; step>0; step>>=1){
        if (tid < step) red[tid] = fmax(red[tid], red[tid+step]);
        __syncthreads();
    }
    if (tid == 0) MM = red[0];
    __syncthreads();
    double M = MM;
    // phase 2: denominator
    double dsum = 0.0;
    for (int j=tid; j<dg; j+=256){
        int s = csr_src[o0+j];
        double e = lrelu(hs1[s] + hdt);
        dsum += fexp(e - M);
    }
    red[tid] = dsum; __syncthreads();
    for (int step=128; step>0; step>>=1){
        if (tid < step) red[tid] += red[tid+step];
        __syncthreads();
    }
    if (tid == 0) DD = red[0];
    __syncthreads();
    double Dv = DD;
    // phase 3: weighted gather
    double acc[5] = {0,0,0,0,0};
    for (int base=0; base<dg; base+=256){
        int j = base + tid;
        if (j < dg){
            int s = csr_src[o0+j];
            double e = lrelu(hs1[s] + hdt);
            als[tid] = fexp(e - M)/Dv; ssrc[tid] = s;
        }
        __syncthreads();
        int lim = min(256, dg-base);
        for (int u=0; u<lim; u+=2){
            double a0 = als[u];
            int s0 = ssrc[u];
            bool h1 = (u+1 < lim);
            double a1 = h1 ? als[u+1] : 0.0;
            int s1 = h1 ? ssrc[u+1] : s0;
            const double* hp0 = &h64[(size_t)s0*D];
            const double* hp1 = &h64[(size_t)s1*D];
            #pragma unroll
            for (int q=0; q<5; q++)
                acc[q] += a0 * hp0[tid + 256*q] + a1 * hp1[tid + 256*q];
        }
        __syncthreads();
    }
    #pragma unroll
    for (int q=0; q<5; q++){
        int d = tid + 256*q;
        g64[(size_t)t*D + d] = (acc[q] + (double)b1[d]) * (double)w2[d];
    }
}

// ---- sparse H2 (unchanged from R5: cache-BW bound, rewrite planned next round)
__global__ __launch_bounds__(256, 2)
void k_h2(const double* __restrict__ g64, const float* __restrict__ xo,
          const u16* __restrict__ cols, const int* __restrict__ cnt,
          double* __restrict__ H2){
    int b = blockIdx.x;
    int chunk = b & (NCH-1);
    int tid = threadIdx.x, wv = tid >> 6, ln = tid & 63;
    int i = ((b >> 3) << 2) + wv;
    double gr[5][4];
    #pragma unroll
    for (int k=0; k<5; k++){
        #pragma unroll
        for (int c=0; c<4; c++) gr[k][c] = g64[(size_t)i*D + ln*4 + 256*k + c];
    }
    int c0 = cnt[i];
    const u16* cp = &cols[(size_t)i*N];
    int v0 = chunk*CHW;
    int lo = lbound(cp, c0, v0);
    int hi = lbound(cp, c0, v0 + CHW);
    for (int cb = lo; cb < hi; cb += 4){
        int e1 = (cb+1 < hi) ? cb+1 : cb;
        int e2 = (cb+2 < hi) ? cb+2 : cb;
        int e3 = (cb+3 < hi) ? cb+3 : cb;
        int j0 = cp[cb], j1 = cp[e1], j2 = cp[e2], j3 = cp[e3];
        const float4* p0 = (const float4*)(&xo[(size_t)j0*D]) + ln;
        const float4* p1 = (const float4*)(&xo[(size_t)j1*D]) + ln;
        const float4* p2 = (const float4*)(&xo[(size_t)j2*D]) + ln;
        const float4* p3 = (const float4*)(&xo[(size_t)j3*D]) + ln;
        double a0 = 0.0, a1 = 0.0, a2 = 0.0, a3 = 0.0;
        #pragma unroll
        for (int k=0; k<5; k++){
            float4 w0 = p0[64*k];
            float4 w1 = p1[64*k];
            float4 w2v = p2[64*k];
            float4 w3 = p3[64*k];
            a0 += gr[k][0]*(double)w0.x + gr[k][1]*(double)w0.y
                + gr[k][2]*(double)w0.z + gr[k][3]*(double)w0.w;
            a1 += gr[k][0]*(double)w1.x + gr[k][1]*(double)w1.y
                + gr[k][2]*(double)w1.z + gr[k][3]*(double)w1.w;
            a2 += gr[k][0]*(double)w2v.x + gr[k][1]*(double)w2v.y
                + gr[k][2]*(double)w2v.z + gr[k][3]*(double)w2v.w;
            a3 += gr[k][0]*(double)w3.x + gr[k][1]*(double)w3.y
                + gr[k][2]*(double)w3.z + gr[k][3]*(double)w3.w;
        }
        #pragma unroll
        for (int o=32; o>0; o>>=1){
            a0 += __shfl_down(a0, o, 64);
            a1 += __shfl_down(a1, o, 64);
            a2 += __shfl_down(a2, o, 64);
            a3 += __shfl_down(a3, o, 64);
        }
        if (ln == 0){
            H2[(size_t)i*N + j0] = a0;
            if (cb+1 < hi) H2[(size_t)i*N + j1] = a1;
            if (cb+2 < hi) H2[(size_t)i*N + j2] = a2;
            if (cb+3 < hi) H2[(size_t)i*N + j3] = a3;
        }
    }
}

// ---- fused stage-2 score + rank: 2-pass branch-free softmax with fexp
__global__ void k_score_rank(const double* __restrict__ H2, const u64* __restrict__ Mb,
                             const u16* __restrict__ cols, const int* __restrict__ cnt,
                             const int* __restrict__ coff, const int* __restrict__ csr_src,
                             const float* __restrict__ pas2, const float* __restrict__ pad2,
                             const float* __restrict__ pb2, float* __restrict__ out){
    int i = blockIdx.x, tid = threadIdx.x;
    __shared__ double HL[N];     // 12 KB
    __shared__ u64 MbL[NW];
    __shared__ double scL[N];    // 12 KB
    __shared__ u16 clL[N];       // 3 KB
    float* keepO = out + (size_t)N*N;
    for (int c=tid; c<N; c+=256){
        out[(size_t)i*N + c]   = 0.0f;
        keepO[(size_t)i*N + c] = 0.0f;
    }
    for (int d=tid; d<N; d+=256) HL[d] = H2[(size_t)i*N + d];
    if (tid < NW) MbL[tid] = Mb[(size_t)i*NW + tid];
    __syncthreads();
    double as2 = (double)pas2[0], ad2 = (double)pad2[0], b2 = (double)pb2[0];
    int c0 = cnt[i];
    for (int c=tid; c<c0; c+=256){
        int t = cols[(size_t)i*N + c];
        double ht = HL[t];
        int o0 = coff[t], o1 = coff[t+1];
        // pass A: max over valid (branch-free)
        double m = -1e300;
        for (int p=o0; p<o1; p++){
            int s = csr_src[p];
            bool v = (MbL[s>>6] >> (s&63)) & 1ULL;
            double z = as2*HL[s] + ad2*ht;
            double e = z > 0.0 ? z : 0.2*z;
            m = fmax(m, v ? e : -1e300);
        }
        // pass B: uniform fexp accumulation (invalid -> weight 0)
        double den = 0.0, nu = 0.0;
        for (int p=o0; p<o1; p++){
            int s = csr_src[p];
            bool v = (MbL[s>>6] >> (s&63)) & 1ULL;
            double hs = HL[s];
            double z = as2*hs + ad2*ht;
            double e = z > 0.0 ? z : 0.2*z;
            double w = fexp(v ? e - m : -1000.0);
            den += w;
            nu = __builtin_fma(w, hs, nu);
        }
        scL[c] = nu / fmax(den, 1e-12) + b2;
        clL[c] = (u16)t;
    }
    __syncthreads();
    int k = (c0 + 1) >> 1;                 // ceil(0.5*size)
    for (int p=tid; p<c0; p+=256){
        double s = scL[p]; int col = clL[p];
        int r = 0;
        for (int q=0; q<c0; q++){
            double sq = scL[q];
            r += (int)((sq > s) | ((sq == s) & (clL[q] < col)));
        }
        if (r < k){
            out[(size_t)i*N + col]   = (float)(1.0/(1.0 + fexp(-s)));
            keepO[(size_t)i*N + col] = 1.0f;
        }
    }
}

extern "C" void kernel_launch(void* const* d_in, const int* in_sizes, int n_in,
                              void* d_out, int out_size, void* d_ws, size_t ws_size,
                              hipStream_t stream){
    const float* x   = (const float*)d_in[0];
    const float* xo  = (const float*)d_in[1];
    const int*   ei  = (const int*)  d_in[2];
    // d_in[3] = batch (unused)
    const float* W1  = (const float*)d_in[4];
    const float* as1 = (const float*)d_in[5];
    const float* ad1 = (const float*)d_in[6];
    const float* b1  = (const float*)d_in[7];
    const float* w2  = (const float*)d_in[8];
    const float* as2 = (const float*)d_in[9];
    const float* ad2 = (const float*)d_in[10];
    const float* b2  = (const float*)d_in[11];
    float* out = (float*)d_out;

    char* w = (char*)d_ws;
    size_t o = 0;
    auto alloc = [&](size_t b)->char*{ char* r = w + o; o = (o + b + 255) & ~(size_t)255; return r; };

    double* h64   = (double*)alloc((size_t)N*D*8);
    double* g64   = (double*)alloc((size_t)N*D*8);
    double* H2    = (double*)alloc((size_t)N*N*8);
    u64*    IN    = (u64*)   alloc((size_t)N*NW*8);
    u64*    Mb    = (u64*)   alloc((size_t)N*NW*8);
    double* hs1   = (double*)alloc((size_t)N*8);
    double* hd1   = (double*)alloc((size_t)N*8);
    int*    deg   = (int*)   alloc((size_t)N*4);
    int*    coff  = (int*)   alloc((size_t)(N+1)*4);
    int*    cursor= (int*)   alloc((size_t)N*4);
    int*    csr   = (int*)   alloc((size_t)(E+N)*4);
    u16*    cols  = (u16*)   alloc((size_t)N*N*2);
    int*    cnt   = (int*)   alloc((size_t)N*4);

    hipMemsetAsync(IN,  0, (size_t)N*NW*8, stream);
    hipMemsetAsync(deg, 0, (size_t)N*4,    stream);

    k_deg_in<<<(E+N+255)/256, 256, 0, stream>>>(ei, IN, deg);
    k_scan  <<<1, 256, 0, stream>>>(deg, coff, cursor);
    k_fill  <<<(E+N+255)/256, 256, 0, stream>>>(ei, cursor, csr);
    k_mrow  <<<N, 64, 0, stream>>>(IN, Mb, cols, cnt);
    k_h     <<<dim3(D/256, N/RT), 256, 0, stream>>>(x, W1, h64);
    k_hv    <<<N, 256, 0, stream>>>(h64, as1, ad1, hs1, hd1);
    k_gat   <<<N, 256, 0, stream>>>(coff, csr, hs1, hd1, h64, b1, w2, g64);
    k_h2    <<<(N/4)*NCH, 256, 0, stream>>>(g64, xo, cols, cnt, H2);
    k_score_rank<<<N, 256, 0, stream>>>(H2, Mb, cols, cnt, coff, csr, as2, ad2, b2, out);
}

// Round 7
// 331.278 us; speedup vs baseline: 1.2541x; 1.1525x over previous
//
#include <hip/hip_runtime.h>
#include <math.h>

#define N 1536
#define E 24576
#define HD 128
#define D 1280
#define NW 24    // 1536/64 bitmask words per row
#define RT 16    // rows per block in k_h
#define NCH 16   // j-chunks in k_h2
#define CHW 96   // chunk width

typedef unsigned long long u64;
typedef unsigned short u16;

__device__ __forceinline__ double lrelu(double v){ return v > 0.0 ? v : 0.2*v; }

// Branch-free exp(x), rel err ~6e-15. Valid for |x| <= ~700; x < -700 -> 0.
__device__ __forceinline__ double fexp(double x){
    double n = __builtin_rint(x * 1.4426950408889634);
    double r = __builtin_fma(-n, 0.6931471805599453, x);
    r = __builtin_fma(-n, 2.3190468138462996e-17, r);
    double p = 2.505210838544172e-8;
    p = __builtin_fma(p, r, 2.755731922398589e-7);
    p = __builtin_fma(p, r, 2.7557319223985893e-6);
    p = __builtin_fma(p, r, 2.48015873015873e-5);
    p = __builtin_fma(p, r, 1.984126984126984e-4);
    p = __builtin_fma(p, r, 1.3888888888888889e-3);
    p = __builtin_fma(p, r, 8.333333333333333e-3);
    p = __builtin_fma(p, r, 4.1666666666666664e-2);
    p = __builtin_fma(p, r, 1.6666666666666666e-1);
    p = __builtin_fma(p, r, 0.5);
    p = __builtin_fma(p, r, 1.0);
    p = __builtin_fma(p, r, 1.0);
    long long ni = (long long)n;
    double s = __longlong_as_double((u64)(ni + 1023) << 52);
    return (x < -700.0) ? 0.0 : p * s;
}

__device__ __forceinline__ int lbound(const u16* __restrict__ a, int n, int v){
    int lo = 0;
    while (lo < n){ int mid = (lo + n) >> 1; if (a[mid] < v) lo = mid + 1; else n = mid; }
    return lo;
}

// ---- IN bitmask + in-degree incl. self-loop
__global__ void k_deg_in(const int* __restrict__ ei, u64* __restrict__ IN, int* __restrict__ deg){
    int idx = blockIdx.x*blockDim.x + threadIdx.x;
    if (idx < E){
        int s = ei[idx], t = ei[E+idx];
        atomicOr(&IN[(size_t)t*NW + (s>>6)], 1ULL << (s&63));
        atomicAdd(&deg[t], 1);
    } else if (idx < E+N){
        atomicAdd(&deg[idx-E], 1);
    }
}

// ---- exclusive scan of deg -> coff[0..N], cursor copy
__global__ void k_scan(const int* __restrict__ deg, int* __restrict__ coff, int* __restrict__ cursor){
    __shared__ int ls[256];
    int tid = threadIdx.x;
    int v[6]; int s = 0;
    for (int u=0; u<6; u++){ v[u] = s; s += deg[tid*6+u]; }
    ls[tid] = s; __syncthreads();
    for (int d=1; d<256; d<<=1){
        int t2 = (tid>=d) ? ls[tid-d] : 0;
        __syncthreads();
        ls[tid] += t2;
        __syncthreads();
    }
    int base = (tid>0) ? ls[tid-1] : 0;
    for (int u=0; u<6; u++){
        int o = base + v[u];
        coff[tid*6+u] = o; cursor[tid*6+u] = o;
    }
    if (tid==255) coff[N] = ls[255];
}

// ---- fill CSR of in-edge sources
__global__ void k_fill(const int* __restrict__ ei, int* __restrict__ cursor, int* __restrict__ csr_src){
    int idx = blockIdx.x*blockDim.x + threadIdx.x;
    if (idx < E){
        int s = ei[idx], t = ei[E+idx];
        int p = atomicAdd(&cursor[t], 1);
        csr_src[p] = s;
    } else if (idx < E+N){
        int t = idx - E;
        int p = atomicAdd(&cursor[t], 1);
        csr_src[p] = t;
    }
}

// ---- 2-hop reachability. 1-hop node list in LDS, 4 independent OR chains.
__global__ void k_mrow(const u64* __restrict__ IN, u64* __restrict__ Mb,
                       u16* __restrict__ cols, int* __restrict__ cnt){
    int i = blockIdx.x, ln = threadIdx.x;   // blockDim = 64
    __shared__ u64 m1[NW];
    __shared__ int scn[64];
    __shared__ u16 lst[N];
    u64 b = 0;
    if (ln < NW){
        b = IN[(size_t)i*NW + ln];
        if ((i>>6) == ln) b |= 1ULL << (i&63);
        m1[ln] = b;
    }
    int pc = (ln < NW) ? __popcll(b) : 0;
    scn[ln] = pc; __syncthreads();
    for (int d=1; d<64; d<<=1){
        int v = (ln>=d) ? scn[ln-d] : 0;
        __syncthreads();
        scn[ln] += v;
        __syncthreads();
    }
    {
        int idx = scn[ln] - pc;
        u64 bb = b;
        while (bb){
            int k = __ffsll((unsigned long long)bb) - 1;
            bb &= bb - 1;
            lst[idx++] = (u16)(ln*64 + k);
        }
    }
    __syncthreads();
    int nn = scn[63];
    u64 R0 = b, R1 = 0, R2 = 0, R3 = 0;
    int u = 0;
    if (ln < NW){
        for (; u+3 < nn; u += 4){
            R0 |= IN[(size_t)lst[u  ]*NW + ln];
            R1 |= IN[(size_t)lst[u+1]*NW + ln];
            R2 |= IN[(size_t)lst[u+2]*NW + ln];
            R3 |= IN[(size_t)lst[u+3]*NW + ln];
        }
        for (; u < nn; u++) R0 |= IN[(size_t)lst[u]*NW + ln];
    }
    u64 R = (R0 | R1) | (R2 | R3);
    if (ln < NW) Mb[(size_t)i*NW + ln] = R;
    __syncthreads();
    pc = (ln < NW) ? __popcll(R) : 0;
    scn[ln] = pc; __syncthreads();
    for (int d=1; d<64; d<<=1){
        int v = (ln>=d) ? scn[ln-d] : 0;
        __syncthreads();
        scn[ln] += v;
        __syncthreads();
    }
    if (ln == 63) cnt[i] = scn[63];
    int idx = scn[ln] - pc;
    u64 bb = R;
    while (bb){
        int k = __ffsll((unsigned long long)bb) - 1;
        bb &= bb - 1;
        cols[(size_t)i*N + idx++] = (u16)(ln*64 + k);
    }
}

// ---- h = x @ W1, all-f32. grid (D/256, N/RT).
__global__ void k_h(const float* __restrict__ x, const float* __restrict__ W1, float* __restrict__ h32){
    int rb = blockIdx.y*RT, tid = threadIdx.x;
    int col = blockIdx.x*256 + tid;
    __shared__ float xL[RT*HD];   // 8 KB
    for (int u=tid; u<RT*HD; u+=256) xL[u] = x[(size_t)rb*HD + u];
    __syncthreads();
    float acc[RT];
    #pragma unroll
    for (int r=0; r<RT; r++) acc[r] = 0.0f;
    const float* wp = &W1[col];
    #pragma unroll 4
    for (int k=0; k<HD; k++){
        float w = wp[(size_t)k*D];
        #pragma unroll
        for (int r=0; r<RT; r++) acc[r] = __builtin_fmaf(w, xL[r*HD + k], acc[r]);
    }
    #pragma unroll
    for (int r=0; r<RT; r++) h32[(size_t)(rb+r)*D + col] = acc[r];
}

// ---- hs1 = h@a_src1, hd1 = h@a_dst1 (f64 accum over f32 h)
__global__ void k_hv(const float* __restrict__ h32, const float* __restrict__ as1,
                     const float* __restrict__ ad1, double* __restrict__ hs1, double* __restrict__ hd1){
    int i = blockIdx.x, tid = threadIdx.x;
    __shared__ double ra[256], rb[256];
    double a = 0, b = 0;
    for (int d=tid; d<D; d+=256){
        double hv = (double)h32[(size_t)i*D + d];
        a += hv * (double)as1[d];
        b += hv * (double)ad1[d];
    }
    ra[tid] = a; rb[tid] = b; __syncthreads();
    for (int s=128; s>0; s>>=1){
        if (tid < s){ ra[tid] += ra[tid+s]; rb[tid] += rb[tid+s]; }
        __syncthreads();
    }
    if (tid == 0){ hs1[i] = ra[0]; hd1[i] = rb[0]; }
}

// ---- stage-1 GAT: f64 softmax weights, f32 gather
__global__ void k_gat(const int* __restrict__ coff, const int* __restrict__ csr_src,
                      const double* __restrict__ hs1, const double* __restrict__ hd1,
                      const float* __restrict__ h32,
                      const float* __restrict__ b1, const float* __restrict__ w2,
                      float* __restrict__ g32){
    int t = blockIdx.x, tid = threadIdx.x;
    int o0 = coff[t], o1 = coff[t+1], dg = o1 - o0;
    __shared__ double red[256];
    __shared__ float als[256];
    __shared__ int ssrc[256];
    __shared__ double MM, DD;
    double hdt = hd1[t];
    double m = -1e300;
    for (int j=tid; j<dg; j+=256){
        int s = csr_src[o0+j];
        double e = lrelu(hs1[s] + hdt);
        m = fmax(m, e);
    }
    red[tid] = m; __syncthreads();
    for (int step=128; step>0; step>>=1){
        if (tid < step) red[tid] = fmax(red[tid], red[tid+step]);
        __syncthreads();
    }
    if (tid == 0) MM = red[0];
    __syncthreads();
    double M = MM;
    double dsum = 0.0;
    for (int j=tid; j<dg; j+=256){
        int s = csr_src[o0+j];
        double e = lrelu(hs1[s] + hdt);
        dsum += fexp(e - M);
    }
    red[tid] = dsum; __syncthreads();
    for (int step=128; step>0; step>>=1){
        if (tid < step) red[tid] += red[tid+step];
        __syncthreads();
    }
    if (tid == 0) DD = red[0];
    __syncthreads();
    double Dv = DD;
    float acc[5] = {0,0,0,0,0};
    for (int base=0; base<dg; base+=256){
        int j = base + tid;
        if (j < dg){
            int s = csr_src[o0+j];
            double e = lrelu(hs1[s] + hdt);
            als[tid] = (float)(fexp(e - M)/Dv); ssrc[tid] = s;
        }
        __syncthreads();
        int lim = min(256, dg-base);
        for (int u=0; u<lim; u+=2){
            float a0 = als[u];
            int s0 = ssrc[u];
            bool h1 = (u+1 < lim);
            float a1 = h1 ? als[u+1] : 0.0f;
            int s1 = h1 ? ssrc[u+1] : s0;
            const float* hp0 = &h32[(size_t)s0*D];
            const float* hp1 = &h32[(size_t)s1*D];
            #pragma unroll
            for (int q=0; q<5; q++)
                acc[q] = __builtin_fmaf(a1, hp1[tid + 256*q],
                         __builtin_fmaf(a0, hp0[tid + 256*q], acc[q]));
        }
        __syncthreads();
    }
    #pragma unroll
    for (int q=0; q<5; q++){
        int d = tid + 256*q;
        g32[(size_t)t*D + d] = (acc[q] + b1[d]) * w2[d];
    }
}

// ---- sparse H2, all-f32 datapath (f32 FMA, f32 shuffle tree; err ~1e-7 rel)
__global__ __launch_bounds__(256, 4)
void k_h2(const float* __restrict__ g32, const float* __restrict__ xo,
          const u16* __restrict__ cols, const int* __restrict__ cnt,
          float* __restrict__ H2){
    int b = blockIdx.x;
    int chunk = b & (NCH-1);
    int tid = threadIdx.x, wv = tid >> 6, ln = tid & 63;
    int i = ((b >> 4) << 2) + wv;
    float gr[5][4];
    #pragma unroll
    for (int k=0; k<5; k++){
        float4 gv = *((const float4*)(&g32[(size_t)i*D + 256*k]) + ln);
        gr[k][0] = gv.x; gr[k][1] = gv.y; gr[k][2] = gv.z; gr[k][3] = gv.w;
    }
    int c0 = cnt[i];
    const u16* cp = &cols[(size_t)i*N];
    int v0 = chunk*CHW;
    int lo = lbound(cp, c0, v0);
    int hi = lbound(cp, c0, v0 + CHW);
    for (int cb = lo; cb < hi; cb += 4){
        int e1 = (cb+1 < hi) ? cb+1 : cb;
        int e2 = (cb+2 < hi) ? cb+2 : cb;
        int e3 = (cb+3 < hi) ? cb+3 : cb;
        int j0 = cp[cb], j1 = cp[e1], j2 = cp[e2], j3 = cp[e3];
        const float4* p0 = (const float4*)(&xo[(size_t)j0*D]) + ln;
        const float4* p1 = (const float4*)(&xo[(size_t)j1*D]) + ln;
        const float4* p2 = (const float4*)(&xo[(size_t)j2*D]) + ln;
        const float4* p3 = (const float4*)(&xo[(size_t)j3*D]) + ln;
        float a0 = 0.0f, a1 = 0.0f, a2 = 0.0f, a3 = 0.0f;
        #pragma unroll
        for (int k=0; k<5; k++){
            float4 w0 = p0[64*k];
            float4 w1 = p1[64*k];
            float4 w2v = p2[64*k];
            float4 w3 = p3[64*k];
            a0 += gr[k][0]*w0.x + gr[k][1]*w0.y + gr[k][2]*w0.z + gr[k][3]*w0.w;
            a1 += gr[k][0]*w1.x + gr[k][1]*w1.y + gr[k][2]*w1.z + gr[k][3]*w1.w;
            a2 += gr[k][0]*w2v.x + gr[k][1]*w2v.y + gr[k][2]*w2v.z + gr[k][3]*w2v.w;
            a3 += gr[k][0]*w3.x + gr[k][1]*w3.y + gr[k][2]*w3.z + gr[k][3]*w3.w;
        }
        #pragma unroll
        for (int o=32; o>0; o>>=1){
            a0 += __shfl_down(a0, o, 64);
            a1 += __shfl_down(a1, o, 64);
            a2 += __shfl_down(a2, o, 64);
            a3 += __shfl_down(a3, o, 64);
        }
        if (ln == 0){
            H2[(size_t)i*N + j0] = a0;
            if (cb+1 < hi) H2[(size_t)i*N + j1] = a1;
            if (cb+2 < hi) H2[(size_t)i*N + j2] = a2;
            if (cb+3 < hi) H2[(size_t)i*N + j3] = a3;
        }
    }
}

// ---- fused stage-2 score + rank (f32 H2 in LDS, f64 softmax/rank math)
__global__ void k_score_rank(const float* __restrict__ H2, const u64* __restrict__ Mb,
                             const u16* __restrict__ cols, const int* __restrict__ cnt,
                             const int* __restrict__ coff, const int* __restrict__ csr_src,
                             const float* __restrict__ pas2, const float* __restrict__ pad2,
                             const float* __restrict__ pb2, float* __restrict__ out){
    int i = blockIdx.x, tid = threadIdx.x;
    __shared__ float HL[N];      // 6 KB
    __shared__ u64 MbL[NW];
    __shared__ double scL[N];    // 12 KB
    __shared__ u16 clL[N];       // 3 KB
    float* keepO = out + (size_t)N*N;
    for (int c=tid; c<N; c+=256){
        out[(size_t)i*N + c]   = 0.0f;
        keepO[(size_t)i*N + c] = 0.0f;
    }
    for (int d=tid; d<N; d+=256) HL[d] = H2[(size_t)i*N + d];
    if (tid < NW) MbL[tid] = Mb[(size_t)i*NW + tid];
    __syncthreads();
    double as2 = (double)pas2[0], ad2 = (double)pad2[0], b2 = (double)pb2[0];
    int c0 = cnt[i];
    for (int c=tid; c<c0; c+=256){
        int t = cols[(size_t)i*N + c];
        double ht = (double)HL[t];
        int o0 = coff[t], o1 = coff[t+1];
        double m = -1e300;
        for (int p=o0; p<o1; p++){
            int s = csr_src[p];
            bool v = (MbL[s>>6] >> (s&63)) & 1ULL;
            double z = as2*(double)HL[s] + ad2*ht;
            double e = z > 0.0 ? z : 0.2*z;
            m = fmax(m, v ? e : -1e300);
        }
        double den = 0.0, nu = 0.0;
        for (int p=o0; p<o1; p++){
            int s = csr_src[p];
            bool v = (MbL[s>>6] >> (s&63)) & 1ULL;
            double hs = (double)HL[s];
            double z = as2*hs + ad2*ht;
            double e = z > 0.0 ? z : 0.2*z;
            double w = fexp(v ? e - m : -1000.0);
            den += w;
            nu = __builtin_fma(w, hs, nu);
        }
        scL[c] = nu / fmax(den, 1e-12) + b2;
        clL[c] = (u16)t;
    }
    __syncthreads();
    int k = (c0 + 1) >> 1;                 // ceil(0.5*size)
    for (int p=tid; p<c0; p+=256){
        double s = scL[p]; int col = clL[p];
        int r = 0;
        for (int q=0; q<c0; q++){
            double sq = scL[q];
            r += (int)((sq > s) | ((sq == s) & (clL[q] < col)));
        }
        if (r < k){
            out[(size_t)i*N + col]   = (float)(1.0/(1.0 + fexp(-s)));
            keepO[(size_t)i*N + col] = 1.0f;
        }
    }
}

extern "C" void kernel_launch(void* const* d_in, const int* in_sizes, int n_in,
                              void* d_out, int out_size, void* d_ws, size_t ws_size,
                              hipStream_t stream){
    const float* x   = (const float*)d_in[0];
    const float* xo  = (const float*)d_in[1];
    const int*   ei  = (const int*)  d_in[2];
    // d_in[3] = batch (unused)
    const float* W1  = (const float*)d_in[4];
    const float* as1 = (const float*)d_in[5];
    const float* ad1 = (const float*)d_in[6];
    const float* b1  = (const float*)d_in[7];
    const float* w2  = (const float*)d_in[8];
    const float* as2 = (const float*)d_in[9];
    const float* ad2 = (const float*)d_in[10];
    const float* b2  = (const float*)d_in[11];
    float* out = (float*)d_out;

    char* w = (char*)d_ws;
    size_t o = 0;
    auto alloc = [&](size_t b)->char*{ char* r = w + o; o = (o + b + 255) & ~(size_t)255; return r; };

    float*  h32   = (float*) alloc((size_t)N*D*4);
    float*  g32   = (float*) alloc((size_t)N*D*4);
    float*  H2    = (float*) alloc((size_t)N*N*4);
    u64*    IN    = (u64*)   alloc((size_t)N*NW*8);
    u64*    Mb    = (u64*)   alloc((size_t)N*NW*8);
    double* hs1   = (double*)alloc((size_t)N*8);
    double* hd1   = (double*)alloc((size_t)N*8);
    int*    deg   = (int*)   alloc((size_t)N*4);
    int*    coff  = (int*)   alloc((size_t)(N+1)*4);
    int*    cursor= (int*)   alloc((size_t)N*4);
    int*    csr   = (int*)   alloc((size_t)(E+N)*4);
    u16*    cols  = (u16*)   alloc((size_t)N*N*2);
    int*    cnt   = (int*)   alloc((size_t)N*4);

    hipMemsetAsync(IN,  0, (size_t)N*NW*8, stream);
    hipMemsetAsync(deg, 0, (size_t)N*4,    stream);

    k_deg_in<<<(E+N+255)/256, 256, 0, stream>>>(ei, IN, deg);
    k_scan  <<<1, 256, 0, stream>>>(deg, coff, cursor);
    k_fill  <<<(E+N+255)/256, 256, 0, stream>>>(ei, cursor, csr);
    k_mrow  <<<N, 64, 0, stream>>>(IN, Mb, cols, cnt);
    k_h     <<<dim3(D/256, N/RT), 256, 0, stream>>>(x, W1, h32);
    k_hv    <<<N, 256, 0, stream>>>(h32, as1, ad1, hs1, hd1);
    k_gat   <<<N, 256, 0, stream>>>(coff, csr, hs1, hd1, h32, b1, w2, g32);
    k_h2    <<<(N/4)*NCH, 256, 0, stream>>>(g32, xo, cols, cnt, H2);
    k_score_rank<<<N, 256, 0, stream>>>(H2, Mb, cols, cnt, coff, csr, as2, ad2, b2, out);
}

// Round 8
// 291.299 us; speedup vs baseline: 1.4262x; 1.1372x over previous
//
#include <hip/hip_runtime.h>
#include <math.h>

#define N 1536
#define E 24576
#define HD 128
#define D 1280
#define NW 24    // 1536/64 bitmask words per row
#define RT 16    // rows per block in k_h
#define LDK 40   // padded LDS row length (bf16 elems): 80B rows, 16B-aligned frags

typedef unsigned long long u64;
typedef unsigned short u16;
typedef __attribute__((ext_vector_type(8))) short bf16x8;
typedef __attribute__((ext_vector_type(4))) float f32x4;

__device__ __forceinline__ double lrelu(double v){ return v > 0.0 ? v : 0.2*v; }

// Branch-free exp(x), rel err ~6e-15.
__device__ __forceinline__ double fexp(double x){
    double n = __builtin_rint(x * 1.4426950408889634);
    double r = __builtin_fma(-n, 0.6931471805599453, x);
    r = __builtin_fma(-n, 2.3190468138462996e-17, r);
    double p = 2.505210838544172e-8;
    p = __builtin_fma(p, r, 2.755731922398589e-7);
    p = __builtin_fma(p, r, 2.7557319223985893e-6);
    p = __builtin_fma(p, r, 2.48015873015873e-5);
    p = __builtin_fma(p, r, 1.984126984126984e-4);
    p = __builtin_fma(p, r, 1.3888888888888889e-3);
    p = __builtin_fma(p, r, 8.333333333333333e-3);
    p = __builtin_fma(p, r, 4.1666666666666664e-2);
    p = __builtin_fma(p, r, 1.6666666666666666e-1);
    p = __builtin_fma(p, r, 0.5);
    p = __builtin_fma(p, r, 1.0);
    p = __builtin_fma(p, r, 1.0);
    long long ni = (long long)n;
    double s = __longlong_as_double((u64)(ni + 1023) << 52);
    return (x < -700.0) ? 0.0 : p * s;
}

// f32 -> bf16(hi) + bf16(residual), both RNE
__device__ __forceinline__ void bsplit(float f, u16& h, u16& l){
    unsigned u = __float_as_uint(f);
    unsigned hr = (u + 0x7fffu + ((u>>16)&1u)) >> 16;
    h = (u16)hr;
    float hf = __uint_as_float(hr << 16);
    float r = f - hf;
    unsigned u2 = __float_as_uint(r);
    l = (u16)((u2 + 0x7fffu + ((u2>>16)&1u)) >> 16);
}

// ---- IN bitmask + in-degree incl. self-loop
__global__ void k_deg_in(const int* __restrict__ ei, u64* __restrict__ IN, int* __restrict__ deg){
    int idx = blockIdx.x*blockDim.x + threadIdx.x;
    if (idx < E){
        int s = ei[idx], t = ei[E+idx];
        atomicOr(&IN[(size_t)t*NW + (s>>6)], 1ULL << (s&63));
        atomicAdd(&deg[t], 1);
    } else if (idx < E+N){
        atomicAdd(&deg[idx-E], 1);
    }
}

// ---- exclusive scan of deg -> coff[0..N], cursor copy
__global__ void k_scan(const int* __restrict__ deg, int* __restrict__ coff, int* __restrict__ cursor){
    __shared__ int ls[256];
    int tid = threadIdx.x;
    int v[6]; int s = 0;
    for (int u=0; u<6; u++){ v[u] = s; s += deg[tid*6+u]; }
    ls[tid] = s; __syncthreads();
    for (int d=1; d<256; d<<=1){
        int t2 = (tid>=d) ? ls[tid-d] : 0;
        __syncthreads();
        ls[tid] += t2;
        __syncthreads();
    }
    int base = (tid>0) ? ls[tid-1] : 0;
    for (int u=0; u<6; u++){
        int o = base + v[u];
        coff[tid*6+u] = o; cursor[tid*6+u] = o;
    }
    if (tid==255) coff[N] = ls[255];
}

// ---- fill CSR of in-edge sources
__global__ void k_fill(const int* __restrict__ ei, int* __restrict__ cursor, int* __restrict__ csr_src){
    int idx = blockIdx.x*blockDim.x + threadIdx.x;
    if (idx < E){
        int s = ei[idx], t = ei[E+idx];
        int p = atomicAdd(&cursor[t], 1);
        csr_src[p] = s;
    } else if (idx < E+N){
        int t = idx - E;
        int p = atomicAdd(&cursor[t], 1);
        csr_src[p] = t;
    }
}

// ---- 2-hop reachability. 1-hop node list in LDS, 4 independent OR chains.
__global__ void k_mrow(const u64* __restrict__ IN, u64* __restrict__ Mb,
                       u16* __restrict__ cols, int* __restrict__ cnt){
    int i = blockIdx.x, ln = threadIdx.x;   // blockDim = 64
    __shared__ u64 m1[NW];
    __shared__ int scn[64];
    __shared__ u16 lst[N];
    u64 b = 0;
    if (ln < NW){
        b = IN[(size_t)i*NW + ln];
        if ((i>>6) == ln) b |= 1ULL << (i&63);
        m1[ln] = b;
    }
    int pc = (ln < NW) ? __popcll(b) : 0;
    scn[ln] = pc; __syncthreads();
    for (int d=1; d<64; d<<=1){
        int v = (ln>=d) ? scn[ln-d] : 0;
        __syncthreads();
        scn[ln] += v;
        __syncthreads();
    }
    {
        int idx = scn[ln] - pc;
        u64 bb = b;
        while (bb){
            int k = __ffsll((unsigned long long)bb) - 1;
            bb &= bb - 1;
            lst[idx++] = (u16)(ln*64 + k);
        }
    }
    __syncthreads();
    int nn = scn[63];
    u64 R0 = b, R1 = 0, R2 = 0, R3 = 0;
    int u = 0;
    if (ln < NW){
        for (; u+3 < nn; u += 4){
            R0 |= IN[(size_t)lst[u  ]*NW + ln];
            R1 |= IN[(size_t)lst[u+1]*NW + ln];
            R2 |= IN[(size_t)lst[u+2]*NW + ln];
            R3 |= IN[(size_t)lst[u+3]*NW + ln];
        }
        for (; u < nn; u++) R0 |= IN[(size_t)lst[u]*NW + ln];
    }
    u64 R = (R0 | R1) | (R2 | R3);
    if (ln < NW) Mb[(size_t)i*NW + ln] = R;
    __syncthreads();
    pc = (ln < NW) ? __popcll(R) : 0;
    scn[ln] = pc; __syncthreads();
    for (int d=1; d<64; d<<=1){
        int v = (ln>=d) ? scn[ln-d] : 0;
        __syncthreads();
        scn[ln] += v;
        __syncthreads();
    }
    if (ln == 63) cnt[i] = scn[63];
    int idx = scn[ln] - pc;
    u64 bb = R;
    while (bb){
        int k = __ffsll((unsigned long long)bb) - 1;
        bb &= bb - 1;
        cols[(size_t)i*N + idx++] = (u16)(ln*64 + k);
    }
}

// ---- h = x @ W1, all-f32. grid (D/256, N/RT).
__global__ void k_h(const float* __restrict__ x, const float* __restrict__ W1, float* __restrict__ h32){
    int rb = blockIdx.y*RT, tid = threadIdx.x;
    int col = blockIdx.x*256 + tid;
    __shared__ float xL[RT*HD];   // 8 KB
    for (int u=tid; u<RT*HD; u+=256) xL[u] = x[(size_t)rb*HD + u];
    __syncthreads();
    float acc[RT];
    #pragma unroll
    for (int r=0; r<RT; r++) acc[r] = 0.0f;
    const float* wp = &W1[col];
    #pragma unroll 4
    for (int k=0; k<HD; k++){
        float w = wp[(size_t)k*D];
        #pragma unroll
        for (int r=0; r<RT; r++) acc[r] = __builtin_fmaf(w, xL[r*HD + k], acc[r]);
    }
    #pragma unroll
    for (int r=0; r<RT; r++) h32[(size_t)(rb+r)*D + col] = acc[r];
}

// ---- hs1 = h@a_src1, hd1 = h@a_dst1 (f64 accum over f32 h)
__global__ void k_hv(const float* __restrict__ h32, const float* __restrict__ as1,
                     const float* __restrict__ ad1, double* __restrict__ hs1, double* __restrict__ hd1){
    int i = blockIdx.x, tid = threadIdx.x;
    __shared__ double ra[256], rb[256];
    double a = 0, b = 0;
    for (int d=tid; d<D; d+=256){
        double hv = (double)h32[(size_t)i*D + d];
        a += hv * (double)as1[d];
        b += hv * (double)ad1[d];
    }
    ra[tid] = a; rb[tid] = b; __syncthreads();
    for (int s=128; s>0; s>>=1){
        if (tid < s){ ra[tid] += ra[tid+s]; rb[tid] += rb[tid+s]; }
        __syncthreads();
    }
    if (tid == 0){ hs1[i] = ra[0]; hd1[i] = rb[0]; }
}

// ---- split xo into bf16 hi/lo planes
__global__ void k_split_x(const float* __restrict__ xo, u16* __restrict__ Xhi, u16* __restrict__ Xlo){
    int idx = (blockIdx.x*256 + threadIdx.x)*4;
    float4 v = *(const float4*)&xo[idx];
    ushort4 h, l;
    bsplit(v.x, h.x, l.x); bsplit(v.y, h.y, l.y);
    bsplit(v.z, h.z, l.z); bsplit(v.w, h.w, l.w);
    *(ushort4*)&Xhi[idx] = h;
    *(ushort4*)&Xlo[idx] = l;
}

// ---- stage-1 GAT: f64 softmax weights, f32 gather; epilogue emits bf16 hi/lo of g
__global__ void k_gat(const int* __restrict__ coff, const int* __restrict__ csr_src,
                      const double* __restrict__ hs1, const double* __restrict__ hd1,
                      const float* __restrict__ h32,
                      const float* __restrict__ b1, const float* __restrict__ w2,
                      u16* __restrict__ Ghi, u16* __restrict__ Glo){
    int t = blockIdx.x, tid = threadIdx.x;
    int o0 = coff[t], o1 = coff[t+1], dg = o1 - o0;
    __shared__ double red[256];
    __shared__ float als[256];
    __shared__ int ssrc[256];
    __shared__ double MM, DD;
    double hdt = hd1[t];
    double m = -1e300;
    for (int j=tid; j<dg; j+=256){
        int s = csr_src[o0+j];
        double e = lrelu(hs1[s] + hdt);
        m = fmax(m, e);
    }
    red[tid] = m; __syncthreads();
    for (int step=128; step>0; step>>=1){
        if (tid < step) red[tid] = fmax(red[tid], red[tid+step]);
        __syncthreads();
    }
    if (tid == 0) MM = red[0];
    __syncthreads();
    double M = MM;
    double dsum = 0.0;
    for (int j=tid; j<dg; j+=256){
        int s = csr_src[o0+j];
        double e = lrelu(hs1[s] + hdt);
        dsum += fexp(e - M);
    }
    red[tid] = dsum; __syncthreads();
    for (int step=128; step>0; step>>=1){
        if (tid < step) red[tid] += red[tid+step];
        __syncthreads();
    }
    if (tid == 0) DD = red[0];
    __syncthreads();
    double Dv = DD;
    float acc[5] = {0,0,0,0,0};
    for (int base=0; base<dg; base+=256){
        int j = base + tid;
        if (j < dg){
            int s = csr_src[o0+j];
            double e = lrelu(hs1[s] + hdt);
            als[tid] = (float)(fexp(e - M)/Dv); ssrc[tid] = s;
        }
        __syncthreads();
        int lim = min(256, dg-base);
        for (int u=0; u<lim; u+=2){
            float a0 = als[u];
            int s0 = ssrc[u];
            bool h1 = (u+1 < lim);
            float a1 = h1 ? als[u+1] : 0.0f;
            int s1 = h1 ? ssrc[u+1] : s0;
            const float* hp0 = &h32[(size_t)s0*D];
            const float* hp1 = &h32[(size_t)s1*D];
            #pragma unroll
            for (int q=0; q<5; q++)
                acc[q] = __builtin_fmaf(a1, hp1[tid + 256*q],
                         __builtin_fmaf(a0, hp0[tid + 256*q], acc[q]));
        }
        __syncthreads();
    }
    #pragma unroll
    for (int q=0; q<5; q++){
        int d = tid + 256*q;
        float g = (acc[q] + b1[d]) * w2[d];
        u16 gh, gl;
        bsplit(g, gh, gl);
        Ghi[(size_t)t*D + d] = gh;
        Glo[(size_t)t*D + d] = gl;
    }
}

// ---- dense H2 = G @ Xo^T via split-bf16 MFMA (3 passes: hi*hi + lo*hi + hi*lo).
// 128x128 block tile, BK=32, 4 waves each 64x64 (4x4 of 16x16x32 MFMA tiles).
// Layouts per m89/m91-verified formulas.
__global__ __launch_bounds__(256)
void k_h2mm(const u16* __restrict__ Ghi, const u16* __restrict__ Glo,
            const u16* __restrict__ Xhi, const u16* __restrict__ Xlo,
            float* __restrict__ H2){
    __shared__ u16 As_hi[128*LDK], As_lo[128*LDK], Bs_hi[128*LDK], Bs_lo[128*LDK]; // 40 KB
    int tid = threadIdx.x;
    int bm = blockIdx.x / 12, bn = blockIdx.x % 12;
    int r0 = tid >> 2;            // 0..63
    int kc = (tid & 3) * 8;       // 0,8,16,24
    size_t baseA = (size_t)(bm*128 + r0)*D + kc;
    size_t baseB = (size_t)(bn*128 + r0)*D + kc;
    int w = tid >> 6, L = tid & 63;
    int l16 = L & 15, qd = L >> 4;
    int wm = (w & 1)*64, wn = (w >> 1)*64;
    f32x4 acc[4][4];
    #pragma unroll
    for (int a=0; a<4; a++)
        #pragma unroll
        for (int b=0; b<4; b++) acc[a][b] = (f32x4){0.f,0.f,0.f,0.f};

    for (int kb = 0; kb < D; kb += 32){
        uint4 ah0 = *(const uint4*)&Ghi[baseA + kb];
        uint4 ah1 = *(const uint4*)&Ghi[baseA + (size_t)64*D + kb];
        uint4 al0 = *(const uint4*)&Glo[baseA + kb];
        uint4 al1 = *(const uint4*)&Glo[baseA + (size_t)64*D + kb];
        uint4 bh0 = *(const uint4*)&Xhi[baseB + kb];
        uint4 bh1 = *(const uint4*)&Xhi[baseB + (size_t)64*D + kb];
        uint4 bl0 = *(const uint4*)&Xlo[baseB + kb];
        uint4 bl1 = *(const uint4*)&Xlo[baseB + (size_t)64*D + kb];
        __syncthreads();   // previous compute done
        *(uint4*)&As_hi[r0*LDK + kc] = ah0;
        *(uint4*)&As_hi[(r0+64)*LDK + kc] = ah1;
        *(uint4*)&As_lo[r0*LDK + kc] = al0;
        *(uint4*)&As_lo[(r0+64)*LDK + kc] = al1;
        *(uint4*)&Bs_hi[r0*LDK + kc] = bh0;
        *(uint4*)&Bs_hi[(r0+64)*LDK + kc] = bh1;
        *(uint4*)&Bs_lo[r0*LDK + kc] = bl0;
        *(uint4*)&Bs_lo[(r0+64)*LDK + kc] = bl1;
        __syncthreads();   // tiles ready
        bf16x8 ahi[4], alo[4];
        #pragma unroll
        for (int tm=0; tm<4; tm++){
            ahi[tm] = *(const bf16x8*)&As_hi[(wm + tm*16 + l16)*LDK + qd*8];
            alo[tm] = *(const bf16x8*)&As_lo[(wm + tm*16 + l16)*LDK + qd*8];
        }
        #pragma unroll
        for (int tn=0; tn<4; tn++){
            bf16x8 bh = *(const bf16x8*)&Bs_hi[(wn + tn*16 + l16)*LDK + qd*8];
            bf16x8 bl = *(const bf16x8*)&Bs_lo[(wn + tn*16 + l16)*LDK + qd*8];
            #pragma unroll
            for (int tm=0; tm<4; tm++){
                acc[tm][tn] = __builtin_amdgcn_mfma_f32_16x16x32_bf16(ahi[tm], bh, acc[tm][tn], 0, 0, 0);
                acc[tm][tn] = __builtin_amdgcn_mfma_f32_16x16x32_bf16(alo[tm], bh, acc[tm][tn], 0, 0, 0);
                acc[tm][tn] = __builtin_amdgcn_mfma_f32_16x16x32_bf16(ahi[tm], bl, acc[tm][tn], 0, 0, 0);
            }
        }
    }
    // epilogue: C/D layout col=lane&15, row=quad*4+reg
    #pragma unroll
    for (int tm=0; tm<4; tm++){
        int rbase = bm*128 + wm + tm*16 + qd*4;
        #pragma unroll
        for (int tn=0; tn<4; tn++){
            int cg = bn*128 + wn + tn*16 + l16;
            #pragma unroll
            for (int reg=0; reg<4; reg++)
                H2[(size_t)(rbase+reg)*N + cg] = acc[tm][tn][reg];
        }
    }
}

// ---- fused stage-2 score + rank (dense f32 H2, f64 softmax/rank math)
__global__ void k_score_rank(const float* __restrict__ H2, const u64* __restrict__ Mb,
                             const u16* __restrict__ cols, const int* __restrict__ cnt,
                             const int* __restrict__ coff, const int* __restrict__ csr_src,
                             const float* __restrict__ pas2, const float* __restrict__ pad2,
                             const float* __restrict__ pb2, float* __restrict__ out){
    int i = blockIdx.x, tid = threadIdx.x;
    __shared__ float HL[N];      // 6 KB
    __shared__ u64 MbL[NW];
    __shared__ double scL[N];    // 12 KB
    __shared__ u16 clL[N];       // 3 KB
    float* keepO = out + (size_t)N*N;
    for (int c=tid; c<N; c+=256){
        out[(size_t)i*N + c]   = 0.0f;
        keepO[(size_t)i*N + c] = 0.0f;
    }
    for (int d=tid; d<N; d+=256) HL[d] = H2[(size_t)i*N + d];
    if (tid < NW) MbL[tid] = Mb[(size_t)i*NW + tid];
    __syncthreads();
    double as2 = (double)pas2[0], ad2 = (double)pad2[0], b2 = (double)pb2[0];
    int c0 = cnt[i];
    for (int c=tid; c<c0; c+=256){
        int t = cols[(size_t)i*N + c];
        double ht = (double)HL[t];
        int o0 = coff[t], o1 = coff[t+1];
        double m = -1e300;
        for (int p=o0; p<o1; p++){
            int s = csr_src[p];
            bool v = (MbL[s>>6] >> (s&63)) & 1ULL;
            double z = as2*(double)HL[s] + ad2*ht;
            double e = z > 0.0 ? z : 0.2*z;
            m = fmax(m, v ? e : -1e300);
        }
        double den = 0.0, nu = 0.0;
        for (int p=o0; p<o1; p++){
            int s = csr_src[p];
            bool v = (MbL[s>>6] >> (s&63)) & 1ULL;
            double hs = (double)HL[s];
            double z = as2*hs + ad2*ht;
            double e = z > 0.0 ? z : 0.2*z;
            double w = fexp(v ? e - m : -1000.0);
            den += w;
            nu = __builtin_fma(w, hs, nu);
        }
        scL[c] = nu / fmax(den, 1e-12) + b2;
        clL[c] = (u16)t;
    }
    __syncthreads();
    int k = (c0 + 1) >> 1;                 // ceil(0.5*size)
    for (int p=tid; p<c0; p+=256){
        double s = scL[p]; int col = clL[p];
        int r = 0;
        for (int q=0; q<c0; q++){
            double sq = scL[q];
            r += (int)((sq > s) | ((sq == s) & (clL[q] < col)));
        }
        if (r < k){
            out[(size_t)i*N + col]   = (float)(1.0/(1.0 + fexp(-s)));
            keepO[(size_t)i*N + col] = 1.0f;
        }
    }
}

extern "C" void kernel_launch(void* const* d_in, const int* in_sizes, int n_in,
                              void* d_out, int out_size, void* d_ws, size_t ws_size,
                              hipStream_t stream){
    const float* x   = (const float*)d_in[0];
    const float* xo  = (const float*)d_in[1];
    const int*   ei  = (const int*)  d_in[2];
    // d_in[3] = batch (unused)
    const float* W1  = (const float*)d_in[4];
    const float* as1 = (const float*)d_in[5];
    const float* ad1 = (const float*)d_in[6];
    const float* b1  = (const float*)d_in[7];
    const float* w2  = (const float*)d_in[8];
    const float* as2 = (const float*)d_in[9];
    const float* ad2 = (const float*)d_in[10];
    const float* b2  = (const float*)d_in[11];
    float* out = (float*)d_out;

    char* w = (char*)d_ws;
    size_t o = 0;
    auto alloc = [&](size_t b)->char*{ char* r = w + o; o = (o + b + 255) & ~(size_t)255; return r; };

    float*  h32   = (float*) alloc((size_t)N*D*4);
    float*  H2    = (float*) alloc((size_t)N*N*4);
    u16*    Ghi   = (u16*)   alloc((size_t)N*D*2);
    u16*    Glo   = (u16*)   alloc((size_t)N*D*2);
    u16*    Xhi   = (u16*)   alloc((size_t)N*D*2);
    u16*    Xlo   = (u16*)   alloc((size_t)N*D*2);
    u64*    IN    = (u64*)   alloc((size_t)N*NW*8);
    u64*    Mb    = (u64*)   alloc((size_t)N*NW*8);
    double* hs1   = (double*)alloc((size_t)N*8);
    double* hd1   = (double*)alloc((size_t)N*8);
    int*    deg   = (int*)   alloc((size_t)N*4);
    int*    coff  = (int*)   alloc((size_t)(N+1)*4);
    int*    cursor= (int*)   alloc((size_t)N*4);
    int*    csr   = (int*)   alloc((size_t)(E+N)*4);
    u16*    cols  = (u16*)   alloc((size_t)N*N*2);
    int*    cnt   = (int*)   alloc((size_t)N*4);

    hipMemsetAsync(IN,  0, (size_t)N*NW*8, stream);
    hipMemsetAsync(deg, 0, (size_t)N*4,    stream);

    k_deg_in <<<(E+N+255)/256, 256, 0, stream>>>(ei, IN, deg);
    k_scan   <<<1, 256, 0, stream>>>(deg, coff, cursor);
    k_fill   <<<(E+N+255)/256, 256, 0, stream>>>(ei, cursor, csr);
    k_split_x<<<(N*D)/(256*4), 256, 0, stream>>>(xo, Xhi, Xlo);
    k_mrow   <<<N, 64, 0, stream>>>(IN, Mb, cols, cnt);
    k_h      <<<dim3(D/256, N/RT), 256, 0, stream>>>(x, W1, h32);
    k_hv     <<<N, 256, 0, stream>>>(h32, as1, ad1, hs1, hd1);
    k_gat    <<<N, 256, 0, stream>>>(coff, csr, hs1, hd1, h32, b1, w2, Ghi, Glo);
    k_h2mm   <<<144, 256, 0, stream>>>(Ghi, Glo, Xhi, Xlo, H2);
    k_score_rank<<<N, 256, 0, stream>>>(H2, Mb, cols, cnt, coff, csr, as2, ad2, b2, out);
}

// Round 9
// 256.904 us; speedup vs baseline: 1.6172x; 1.1339x over previous
//
#include <hip/hip_runtime.h>
#include <math.h>

#define N 1536
#define E 24576
#define HD 128
#define D 1280
#define NW 24    // 1536/64 bitmask words per row
#define RT 16    // rows per block in k_h
#define LDK 40   // padded LDS row length (bf16 elems)

typedef unsigned long long u64;
typedef unsigned short u16;
typedef unsigned int u32;
typedef __attribute__((ext_vector_type(8))) short bf16x8;
typedef __attribute__((ext_vector_type(4))) float f32x4;

__device__ __forceinline__ double lrelu(double v){ return v > 0.0 ? v : 0.2*v; }

// Branch-free f64 exp(x), rel err ~6e-15.
__device__ __forceinline__ double fexp(double x){
    double n = __builtin_rint(x * 1.4426950408889634);
    double r = __builtin_fma(-n, 0.6931471805599453, x);
    r = __builtin_fma(-n, 2.3190468138462996e-17, r);
    double p = 2.505210838544172e-8;
    p = __builtin_fma(p, r, 2.755731922398589e-7);
    p = __builtin_fma(p, r, 2.7557319223985893e-6);
    p = __builtin_fma(p, r, 2.48015873015873e-5);
    p = __builtin_fma(p, r, 1.984126984126984e-4);
    p = __builtin_fma(p, r, 1.3888888888888889e-3);
    p = __builtin_fma(p, r, 8.333333333333333e-3);
    p = __builtin_fma(p, r, 4.1666666666666664e-2);
    p = __builtin_fma(p, r, 1.6666666666666666e-1);
    p = __builtin_fma(p, r, 0.5);
    p = __builtin_fma(p, r, 1.0);
    p = __builtin_fma(p, r, 1.0);
    long long ni = (long long)n;
    double s = __longlong_as_double((u64)(ni + 1023) << 52);
    return (x < -700.0) ? 0.0 : p * s;
}

// Branch-free f32 exp(x), rel err ~2e-7, valid |x| <= 80.
__device__ __forceinline__ float fexpf_(float x){
    float n = __builtin_rintf(x * 1.44269504f);
    float r = __builtin_fmaf(-n, 0.693359375f, x);       // ln2 hi (exact low bits)
    r = __builtin_fmaf(-n, -2.12194440e-4f, r);          // ln2 lo
    float p = 1.9841270e-4f;                             // 1/7!
    p = __builtin_fmaf(p, r, 1.3888889e-3f);             // 1/6!
    p = __builtin_fmaf(p, r, 8.3333333e-3f);             // 1/5!
    p = __builtin_fmaf(p, r, 4.1666667e-2f);             // 1/4!
    p = __builtin_fmaf(p, r, 1.6666667e-1f);             // 1/3!
    p = __builtin_fmaf(p, r, 0.5f);
    p = __builtin_fmaf(p, r, 1.0f);
    p = __builtin_fmaf(p, r, 1.0f);
    int ni = (int)n;
    float s = __uint_as_float((u32)(ni + 127) << 23);
    return p * s;
}

// f32 -> bf16(hi) + bf16(residual), both RNE
__device__ __forceinline__ void bsplit(float f, u16& h, u16& l){
    unsigned u = __float_as_uint(f);
    unsigned hr = (u + 0x7fffu + ((u>>16)&1u)) >> 16;
    h = (u16)hr;
    float hf = __uint_as_float(hr << 16);
    float r = f - hf;
    unsigned u2 = __float_as_uint(r);
    l = (u16)((u2 + 0x7fffu + ((u2>>16)&1u)) >> 16);
}

// ---- IN bitmask + in-degree incl. self-loop
__global__ void k_deg_in(const int* __restrict__ ei, u64* __restrict__ IN, int* __restrict__ deg){
    int idx = blockIdx.x*blockDim.x + threadIdx.x;
    if (idx < E){
        int s = ei[idx], t = ei[E+idx];
        atomicOr(&IN[(size_t)t*NW + (s>>6)], 1ULL << (s&63));
        atomicAdd(&deg[t], 1);
    } else if (idx < E+N){
        atomicAdd(&deg[idx-E], 1);
    }
}

// ---- exclusive scan of deg -> coff[0..N], cursor copy
__global__ void k_scan(const int* __restrict__ deg, int* __restrict__ coff, int* __restrict__ cursor){
    __shared__ int ls[256];
    int tid = threadIdx.x;
    int v[6]; int s = 0;
    for (int u=0; u<6; u++){ v[u] = s; s += deg[tid*6+u]; }
    ls[tid] = s; __syncthreads();
    for (int d=1; d<256; d<<=1){
        int t2 = (tid>=d) ? ls[tid-d] : 0;
        __syncthreads();
        ls[tid] += t2;
        __syncthreads();
    }
    int base = (tid>0) ? ls[tid-1] : 0;
    for (int u=0; u<6; u++){
        int o = base + v[u];
        coff[tid*6+u] = o; cursor[tid*6+u] = o;
    }
    if (tid==255) coff[N] = ls[255];
}

// ---- fill CSR of in-edge sources
__global__ void k_fill(const int* __restrict__ ei, int* __restrict__ cursor, int* __restrict__ csr_src){
    int idx = blockIdx.x*blockDim.x + threadIdx.x;
    if (idx < E){
        int s = ei[idx], t = ei[E+idx];
        int p = atomicAdd(&cursor[t], 1);
        csr_src[p] = s;
    } else if (idx < E+N){
        int t = idx - E;
        int p = atomicAdd(&cursor[t], 1);
        csr_src[p] = t;
    }
}

// ---- 2-hop reachability. 1-hop node list in LDS, 4 independent OR chains.
__global__ void k_mrow(const u64* __restrict__ IN, u64* __restrict__ Mb,
                       u16* __restrict__ cols, int* __restrict__ cnt){
    int i = blockIdx.x, ln = threadIdx.x;   // blockDim = 64
    __shared__ u64 m1[NW];
    __shared__ int scn[64];
    __shared__ u16 lst[N];
    u64 b = 0;
    if (ln < NW){
        b = IN[(size_t)i*NW + ln];
        if ((i>>6) == ln) b |= 1ULL << (i&63);
        m1[ln] = b;
    }
    int pc = (ln < NW) ? __popcll(b) : 0;
    scn[ln] = pc; __syncthreads();
    for (int d=1; d<64; d<<=1){
        int v = (ln>=d) ? scn[ln-d] : 0;
        __syncthreads();
        scn[ln] += v;
        __syncthreads();
    }
    {
        int idx = scn[ln] - pc;
        u64 bb = b;
        while (bb){
            int k = __ffsll((unsigned long long)bb) - 1;
            bb &= bb - 1;
            lst[idx++] = (u16)(ln*64 + k);
        }
    }
    __syncthreads();
    int nn = scn[63];
    u64 R0 = b, R1 = 0, R2 = 0, R3 = 0;
    int u = 0;
    if (ln < NW){
        for (; u+3 < nn; u += 4){
            R0 |= IN[(size_t)lst[u  ]*NW + ln];
            R1 |= IN[(size_t)lst[u+1]*NW + ln];
            R2 |= IN[(size_t)lst[u+2]*NW + ln];
            R3 |= IN[(size_t)lst[u+3]*NW + ln];
        }
        for (; u < nn; u++) R0 |= IN[(size_t)lst[u]*NW + ln];
    }
    u64 R = (R0 | R1) | (R2 | R3);
    if (ln < NW) Mb[(size_t)i*NW + ln] = R;
    __syncthreads();
    pc = (ln < NW) ? __popcll(R) : 0;
    scn[ln] = pc; __syncthreads();
    for (int d=1; d<64; d<<=1){
        int v = (ln>=d) ? scn[ln-d] : 0;
        __syncthreads();
        scn[ln] += v;
        __syncthreads();
    }
    if (ln == 63) cnt[i] = scn[63];
    int idx = scn[ln] - pc;
    u64 bb = R;
    while (bb){
        int k = __ffsll((unsigned long long)bb) - 1;
        bb &= bb - 1;
        cols[(size_t)i*N + idx++] = (u16)(ln*64 + k);
    }
}

// ---- h = x @ W1, all-f32. grid (D/256, N/RT).
__global__ void k_h(const float* __restrict__ x, const float* __restrict__ W1, float* __restrict__ h32){
    int rb = blockIdx.y*RT, tid = threadIdx.x;
    int col = blockIdx.x*256 + tid;
    __shared__ float xL[RT*HD];   // 8 KB
    for (int u=tid; u<RT*HD; u+=256) xL[u] = x[(size_t)rb*HD + u];
    __syncthreads();
    float acc[RT];
    #pragma unroll
    for (int r=0; r<RT; r++) acc[r] = 0.0f;
    const float* wp = &W1[col];
    #pragma unroll 4
    for (int k=0; k<HD; k++){
        float w = wp[(size_t)k*D];
        #pragma unroll
        for (int r=0; r<RT; r++) acc[r] = __builtin_fmaf(w, xL[r*HD + k], acc[r]);
    }
    #pragma unroll
    for (int r=0; r<RT; r++) h32[(size_t)(rb+r)*D + col] = acc[r];
}

// ---- hs1 = h@a_src1, hd1 = h@a_dst1 (f64 accum over f32 h)
__global__ void k_hv(const float* __restrict__ h32, const float* __restrict__ as1,
                     const float* __restrict__ ad1, double* __restrict__ hs1, double* __restrict__ hd1){
    int i = blockIdx.x, tid = threadIdx.x;
    __shared__ double ra[256], rb[256];
    double a = 0, b = 0;
    for (int d=tid; d<D; d+=256){
        double hv = (double)h32[(size_t)i*D + d];
        a += hv * (double)as1[d];
        b += hv * (double)ad1[d];
    }
    ra[tid] = a; rb[tid] = b; __syncthreads();
    for (int s=128; s>0; s>>=1){
        if (tid < s){ ra[tid] += ra[tid+s]; rb[tid] += rb[tid+s]; }
        __syncthreads();
    }
    if (tid == 0){ hs1[i] = ra[0]; hd1[i] = rb[0]; }
}

// ---- split xo into bf16 hi/lo planes
__global__ void k_split_x(const float* __restrict__ xo, u16* __restrict__ Xhi, u16* __restrict__ Xlo){
    int idx = (blockIdx.x*256 + threadIdx.x)*4;
    float4 v = *(const float4*)&xo[idx];
    ushort4 h, l;
    bsplit(v.x, h.x, l.x); bsplit(v.y, h.y, l.y);
    bsplit(v.z, h.z, l.z); bsplit(v.w, h.w, l.w);
    *(ushort4*)&Xhi[idx] = h;
    *(ushort4*)&Xlo[idx] = l;
}

// ---- stage-1 GAT: single-pass softmax (no max-shift; e is O(1), overflow-safe),
//      f32 gather; epilogue emits bf16 hi/lo of g
__global__ void k_gat(const int* __restrict__ coff, const int* __restrict__ csr_src,
                      const double* __restrict__ hs1, const double* __restrict__ hd1,
                      const float* __restrict__ h32,
                      const float* __restrict__ b1, const float* __restrict__ w2,
                      u16* __restrict__ Ghi, u16* __restrict__ Glo){
    int t = blockIdx.x, tid = threadIdx.x;
    int o0 = coff[t], o1 = coff[t+1], dg = o1 - o0;
    __shared__ double red[256];
    __shared__ float als[256];
    __shared__ int ssrc[256];
    __shared__ double DD;
    double hdt = hd1[t];
    double dsum = 0.0;
    for (int j=tid; j<dg; j+=256){
        int s = csr_src[o0+j];
        double e = lrelu(hs1[s] + hdt);
        dsum += fexp(e);
    }
    red[tid] = dsum; __syncthreads();
    for (int step=128; step>0; step>>=1){
        if (tid < step) red[tid] += red[tid+step];
        __syncthreads();
    }
    if (tid == 0) DD = red[0];
    __syncthreads();
    double Dv = DD;
    float acc[5] = {0,0,0,0,0};
    for (int base=0; base<dg; base+=256){
        int j = base + tid;
        if (j < dg){
            int s = csr_src[o0+j];
            double e = lrelu(hs1[s] + hdt);
            als[tid] = (float)(fexp(e)/Dv); ssrc[tid] = s;
        }
        __syncthreads();
        int lim = min(256, dg-base);
        for (int u=0; u<lim; u+=2){
            float a0 = als[u];
            int s0 = ssrc[u];
            bool h1 = (u+1 < lim);
            float a1 = h1 ? als[u+1] : 0.0f;
            int s1 = h1 ? ssrc[u+1] : s0;
            const float* hp0 = &h32[(size_t)s0*D];
            const float* hp1 = &h32[(size_t)s1*D];
            #pragma unroll
            for (int q=0; q<5; q++)
                acc[q] = __builtin_fmaf(a1, hp1[tid + 256*q],
                         __builtin_fmaf(a0, hp0[tid + 256*q], acc[q]));
        }
        __syncthreads();
    }
    #pragma unroll
    for (int q=0; q<5; q++){
        int d = tid + 256*q;
        float g = (acc[q] + b1[d]) * w2[d];
        u16 gh, gl;
        bsplit(g, gh, gl);
        Ghi[(size_t)t*D + d] = gh;
        Glo[(size_t)t*D + d] = gl;
    }
}

// ---- dense H2 = G @ Xo^T via split-bf16 MFMA (hi*hi + lo*hi + hi*lo).
__global__ __launch_bounds__(256)
void k_h2mm(const u16* __restrict__ Ghi, const u16* __restrict__ Glo,
            const u16* __restrict__ Xhi, const u16* __restrict__ Xlo,
            float* __restrict__ H2){
    __shared__ u16 As_hi[128*LDK], As_lo[128*LDK], Bs_hi[128*LDK], Bs_lo[128*LDK]; // 40 KB
    int tid = threadIdx.x;
    int bm = blockIdx.x / 12, bn = blockIdx.x % 12;
    int r0 = tid >> 2;            // 0..63
    int kc = (tid & 3) * 8;       // 0,8,16,24
    size_t baseA = (size_t)(bm*128 + r0)*D + kc;
    size_t baseB = (size_t)(bn*128 + r0)*D + kc;
    int w = tid >> 6, L = tid & 63;
    int l16 = L & 15, qd = L >> 4;
    int wm = (w & 1)*64, wn = (w >> 1)*64;
    f32x4 acc[4][4];
    #pragma unroll
    for (int a=0; a<4; a++)
        #pragma unroll
        for (int b=0; b<4; b++) acc[a][b] = (f32x4){0.f,0.f,0.f,0.f};

    for (int kb = 0; kb < D; kb += 32){
        uint4 ah0 = *(const uint4*)&Ghi[baseA + kb];
        uint4 ah1 = *(const uint4*)&Ghi[baseA + (size_t)64*D + kb];
        uint4 al0 = *(const uint4*)&Glo[baseA + kb];
        uint4 al1 = *(const uint4*)&Glo[baseA + (size_t)64*D + kb];
        uint4 bh0 = *(const uint4*)&Xhi[baseB + kb];
        uint4 bh1 = *(const uint4*)&Xhi[baseB + (size_t)64*D + kb];
        uint4 bl0 = *(const uint4*)&Xlo[baseB + kb];
        uint4 bl1 = *(const uint4*)&Xlo[baseB + (size_t)64*D + kb];
        __syncthreads();
        *(uint4*)&As_hi[r0*LDK + kc] = ah0;
        *(uint4*)&As_hi[(r0+64)*LDK + kc] = ah1;
        *(uint4*)&As_lo[r0*LDK + kc] = al0;
        *(uint4*)&As_lo[(r0+64)*LDK + kc] = al1;
        *(uint4*)&Bs_hi[r0*LDK + kc] = bh0;
        *(uint4*)&Bs_hi[(r0+64)*LDK + kc] = bh1;
        *(uint4*)&Bs_lo[r0*LDK + kc] = bl0;
        *(uint4*)&Bs_lo[(r0+64)*LDK + kc] = bl1;
        __syncthreads();
        bf16x8 ahi[4], alo[4];
        #pragma unroll
        for (int tm=0; tm<4; tm++){
            ahi[tm] = *(const bf16x8*)&As_hi[(wm + tm*16 + l16)*LDK + qd*8];
            alo[tm] = *(const bf16x8*)&As_lo[(wm + tm*16 + l16)*LDK + qd*8];
        }
        #pragma unroll
        for (int tn=0; tn<4; tn++){
            bf16x8 bh = *(const bf16x8*)&Bs_hi[(wn + tn*16 + l16)*LDK + qd*8];
            bf16x8 bl = *(const bf16x8*)&Bs_lo[(wn + tn*16 + l16)*LDK + qd*8];
            #pragma unroll
            for (int tm=0; tm<4; tm++){
                acc[tm][tn] = __builtin_amdgcn_mfma_f32_16x16x32_bf16(ahi[tm], bh, acc[tm][tn], 0, 0, 0);
                acc[tm][tn] = __builtin_amdgcn_mfma_f32_16x16x32_bf16(alo[tm], bh, acc[tm][tn], 0, 0, 0);
                acc[tm][tn] = __builtin_amdgcn_mfma_f32_16x16x32_bf16(ahi[tm], bl, acc[tm][tn], 0, 0, 0);
            }
        }
    }
    #pragma unroll
    for (int tm=0; tm<4; tm++){
        int rbase = bm*128 + wm + tm*16 + qd*4;
        #pragma unroll
        for (int tn=0; tn<4; tn++){
            int cg = bn*128 + wn + tn*16 + l16;
            #pragma unroll
            for (int reg=0; reg<4; reg++)
                H2[(size_t)(rbase+reg)*N + cg] = acc[tm][tn][reg];
        }
    }
}

// ---- fused stage-2 score + rank v3:
// single-pass softmax (no max-shift; |e| clamped to 80), f32 exp / f64 accum,
// rank via packed u64 keys from f32 scores (matches np's f32 tie semantics).
__global__ void k_score_rank(const float* __restrict__ H2, const u64* __restrict__ Mb,
                             const u16* __restrict__ cols, const int* __restrict__ cnt,
                             const int* __restrict__ coff, const int* __restrict__ csr_src,
                             const float* __restrict__ pas2, const float* __restrict__ pad2,
                             const float* __restrict__ pb2, float* __restrict__ out){
    int i = blockIdx.x, tid = threadIdx.x;
    __shared__ float HL[N];      // 6 KB
    __shared__ u64 MbL[NW];
    __shared__ float scLf[N];    // 6 KB
    __shared__ u16 clL[N];       // 3 KB
    __shared__ u64 KL[N];        // 12 KB
    float* keepO = out + (size_t)N*N;
    for (int c=tid; c<N; c+=256){
        out[(size_t)i*N + c]   = 0.0f;
        keepO[(size_t)i*N + c] = 0.0f;
    }
    for (int d=tid; d<N; d+=256) HL[d] = H2[(size_t)i*N + d];
    if (tid < NW) MbL[tid] = Mb[(size_t)i*NW + tid];
    __syncthreads();
    float as2 = pas2[0], ad2 = pad2[0];
    double b2 = (double)pb2[0];
    int c0 = cnt[i];
    for (int c=tid; c<c0; c+=256){
        int t = cols[(size_t)i*N + c];
        float ht = HL[t];
        float zd = ad2 * ht;
        int o0 = coff[t], o1 = coff[t+1];
        double den = 0.0, nu = 0.0;
        for (int p=o0; p<o1; p++){
            int s = csr_src[p];
            bool v = (MbL[s>>6] >> (s&63)) & 1ULL;
            float hs = HL[s];
            float z = __builtin_fmaf(as2, hs, zd);
            float e = z > 0.0f ? z : 0.2f*z;
            e = fminf(fmaxf(e, -80.0f), 80.0f);
            float w = v ? fexpf_(e) : 0.0f;
            den += (double)w;
            nu  += (double)(w * hs);
        }
        float sf = (float)(nu / fmax(den, 1e-12) + b2);
        scLf[c] = sf;
        clL[c] = (u16)t;
        u32 kb = __float_as_uint(sf);
        kb = (kb & 0x80000000u) ? ~kb : (kb | 0x80000000u);   // order-preserving map
        KL[c] = ((u64)kb << 16) | (u32)(1535 - t);            // tie-break: smaller col wins
    }
    __syncthreads();
    int k = (c0 + 1) >> 1;                 // ceil(0.5*size)
    for (int p=tid; p<c0; p+=256){
        u64 Kp = KL[p];
        int r = 0;
        for (int q=0; q<c0; q++) r += (int)(KL[q] > Kp);
        if (r < k){
            float sf = scLf[p];
            int col = clL[p];
            out[(size_t)i*N + col]   = 1.0f/(1.0f + fexpf_(fminf(fmaxf(-sf,-80.f),80.f)));
            keepO[(size_t)i*N + col] = 1.0f;
        }
    }
}

extern "C" void kernel_launch(void* const* d_in, const int* in_sizes, int n_in,
                              void* d_out, int out_size, void* d_ws, size_t ws_size,
                              hipStream_t stream){
    const float* x   = (const float*)d_in[0];
    const float* xo  = (const float*)d_in[1];
    const int*   ei  = (const int*)  d_in[2];
    // d_in[3] = batch (unused)
    const float* W1  = (const float*)d_in[4];
    const float* as1 = (const float*)d_in[5];
    const float* ad1 = (const float*)d_in[6];
    const float* b1  = (const float*)d_in[7];
    const float* w2  = (const float*)d_in[8];
    const float* as2 = (const float*)d_in[9];
    const float* ad2 = (const float*)d_in[10];
    const float* b2  = (const float*)d_in[11];
    float* out = (float*)d_out;

    char* w = (char*)d_ws;
    size_t o = 0;
    auto alloc = [&](size_t b)->char*{ char* r = w + o; o = (o + b + 255) & ~(size_t)255; return r; };

    float*  h32   = (float*) alloc((size_t)N*D*4);
    float*  H2    = (float*) alloc((size_t)N*N*4);
    u16*    Ghi   = (u16*)   alloc((size_t)N*D*2);
    u16*    Glo   = (u16*)   alloc((size_t)N*D*2);
    u16*    Xhi   = (u16*)   alloc((size_t)N*D*2);
    u16*    Xlo   = (u16*)   alloc((size_t)N*D*2);
    u64*    IN    = (u64*)   alloc((size_t)N*NW*8);
    u64*    Mb    = (u64*)   alloc((size_t)N*NW*8);
    double* hs1   = (double*)alloc((size_t)N*8);
    double* hd1   = (double*)alloc((size_t)N*8);
    int*    deg   = (int*)   alloc((size_t)N*4);
    int*    coff  = (int*)   alloc((size_t)(N+1)*4);
    int*    cursor= (int*)   alloc((size_t)N*4);
    int*    csr   = (int*)   alloc((size_t)(E+N)*4);
    u16*    cols  = (u16*)   alloc((size_t)N*N*2);
    int*    cnt   = (int*)   alloc((size_t)N*4);

    hipMemsetAsync(IN,  0, (size_t)N*NW*8, stream);
    hipMemsetAsync(deg, 0, (size_t)N*4,    stream);

    k_deg_in <<<(E+N+255)/256, 256, 0, stream>>>(ei, IN, deg);
    k_scan   <<<1, 256, 0, stream>>>(deg, coff, cursor);
    k_fill   <<<(E+N+255)/256, 256, 0, stream>>>(ei, cursor, csr);
    k_split_x<<<(N*D)/(256*4), 256, 0, stream>>>(xo, Xhi, Xlo);
    k_mrow   <<<N, 64, 0, stream>>>(IN, Mb, cols, cnt);
    k_h      <<<dim3(D/256, N/RT), 256, 0, stream>>>(x, W1, h32);
    k_hv     <<<N, 256, 0, stream>>>(h32, as1, ad1, hs1, hd1);
    k_gat    <<<N, 256, 0, stream>>>(coff, csr, hs1, hd1, h32, b1, w2, Ghi, Glo);
    k_h2mm   <<<144, 256, 0, stream>>>(Ghi, Glo, Xhi, Xlo, H2);
    k_score_rank<<<N, 256, 0, stream>>>(H2, Mb, cols, cnt, coff, csr, as2, ad2, b2, out);
}